// Round 10
// baseline (175.811 us; speedup 1.0000x reference)
//
#include <hip/hip_runtime.h>

// DynamicConvolution fused pipeline for MI355X (gfx950).
// R10: attention = single kFA built as "kB with P-staging replaced by QK".
// Per WG (64 q-rows, o-half 128): m-loop 64/chunk: [K-frag loads + V-stage
// loads + QK MFMA from regs] -> barrier -> [exp->swizzled P LDS + V LDS
// writes] -> barrier -> [kB's exact frag reads + PV MFMA]. Q frags hoisted.
// QK duplicated per o-half (cheap) so WGs are fully independent; row-sums are
// wave-local. Deletes kA/kB/sbuf/Pbuf (~160 MB HBM traffic removed).
// Stages: k0w -> k0_tt -> k2 qkv -> k3 params -> kFA attn+tmax -> k5 -> k6.

typedef __attribute__((ext_vector_type(8))) short short8;
typedef __attribute__((ext_vector_type(4))) short short4v;
typedef __attribute__((ext_vector_type(4))) float f32x4;

__device__ __forceinline__ unsigned short f2bf(float f){
  unsigned u = __float_as_uint(f);
  u += 0x7FFFu + ((u >> 16) & 1u);           // round-to-nearest-even
  return (unsigned short)(u >> 16);
}
// monotone float<->uint for atomicMax on floats (incl. negatives)
__device__ __forceinline__ unsigned fenc(float f){
  unsigned u = __float_as_uint(f);
  return (u & 0x80000000u) ? ~u : (u | 0x80000000u);
}
__device__ __forceinline__ float fdec(unsigned k){
  unsigned u = (k & 0x80000000u) ? (k & 0x7FFFFFFFu) : ~k;
  return __uint_as_float(u);
}

// ---------------- k0w: Wbf[384][256] bf16 (q*0.125 folded); init tmaxe/pooledEnc -
__global__ __launch_bounds__(256) void k0w(const float* __restrict__ qw,
    const float* __restrict__ kw, const float* __restrict__ vw,
    unsigned short* __restrict__ Wbf, unsigned* __restrict__ tmaxe,
    unsigned* __restrict__ pooledEnc){
  if (blockIdx.x == 0){
    const unsigned ninf = fenc(-3.0e38f);
    for (int i = threadIdx.x; i < 2048; i += 256){
      tmaxe[i] = 0u;                          // floor for encoded O-max
      pooledEnc[i] = ninf;                    // true -inf floor for pooled max
    }
  }
  const int e = (blockIdx.x * 256 + threadIdx.x) * 4;   // 96 WGs * 1024 = 98304
  const int row = e >> 8, c = e & 255;
  const float* src;
  float scl = 1.0f;
  if (row < 64){ src = qw + row * 256 + c; scl = 0.125f; }
  else if (row < 128){ src = kw + (row - 64) * 256 + c; }
  else { src = vw + (row - 128) * 256 + c; }
  float4 v = *(const float4*)src;
  short4v o;
  o[0] = (short)f2bf(v.x * scl); o[1] = (short)f2bf(v.y * scl);
  o[2] = (short)f2bf(v.z * scl); o[3] = (short)f2bf(v.w * scl);
  *(short4v*)(Wbf + e) = o;
}

// ---------------- k0_tt: Tt[b][n][c] = bf16(T[b][c][n]); pooled max fold ---------
__global__ __launch_bounds__(256) void k0_tt(const float* __restrict__ T,
    unsigned short* __restrict__ Tt, unsigned* __restrict__ pooledEnc){
  const int b = blockIdx.x, nt = blockIdx.y, ct = blockIdx.z;
  const int n0 = nt * 128, c0 = ct * 32;
  const int tid = threadIdx.x;
  __shared__ float Ls[32][129];
  const int cr = tid >> 3, nq = tid & 7;      // 32 c-rows x 8 n-chunks(16 f32)
  const float* src = T + ((size_t)b * 256 + c0 + cr) * 2048 + n0 + nq * 16;
  float4 v0 = ((const float4*)src)[0];
  float4 v1 = ((const float4*)src)[1];
  float4 v2 = ((const float4*)src)[2];
  float4 v3 = ((const float4*)src)[3];
  float mx = fmaxf(fmaxf(fmaxf(v0.x, v0.y), fmaxf(v0.z, v0.w)),
                   fmaxf(fmaxf(v1.x, v1.y), fmaxf(v1.z, v1.w)));
  mx = fmaxf(mx, fmaxf(fmaxf(fmaxf(v2.x, v2.y), fmaxf(v2.z, v2.w)),
                       fmaxf(fmaxf(v3.x, v3.y), fmaxf(v3.z, v3.w))));
  mx = fmaxf(mx, __shfl_xor(mx, 1));
  mx = fmaxf(mx, __shfl_xor(mx, 2));
  mx = fmaxf(mx, __shfl_xor(mx, 4));
  if (nq == 0) atomicMax(&pooledEnc[b * 256 + c0 + cr], fenc(mx));
  float* lr = &Ls[cr][nq * 16];
  *(float4*)lr = v0; *(float4*)(lr + 4) = v1;
  *(float4*)(lr + 8) = v2; *(float4*)(lr + 12) = v3;
  __syncthreads();
  const int nr = tid >> 1, ch = tid & 1;      // 128 n-rows x 2 c-halves(16)
  unsigned short ob[16];
  #pragma unroll
  for (int j = 0; j < 16; j++) ob[j] = f2bf(Ls[ch * 16 + j][nr]);
  unsigned short* dst = Tt + ((size_t)b * 2048 + n0 + nr) * 256 + c0 + ch * 16;
  *(short8*)dst = *(short8*)&ob[0];
  *(short8*)(dst + 8) = *(short8*)&ob[8];
}

// ---------------- k2: QKV gemm, kA-shaped (no LDS, direct global frags) ----------
__global__ __launch_bounds__(256) void k2_qkv(const unsigned short* __restrict__ Wbf,
    const unsigned short* __restrict__ Tt,
    unsigned short* __restrict__ qo, unsigned short* __restrict__ ko,
    unsigned short* __restrict__ vt){
  const int wg = blockIdx.x;
  const int b = wg & 7, nt = wg >> 3;
  const int n0 = nt * 32;
  const int tid = threadIdx.x, lane = tid & 63, w = tid >> 6;
  const int l15 = lane & 15, g = lane >> 4;
  const unsigned short* Tb = Tt + (size_t)b * 2048 * 256;

  f32x4 aqk[2][2], av[4][2];
  #pragma unroll
  for (int i = 0; i < 2; i++)
    #pragma unroll
    for (int nf = 0; nf < 2; nf++) aqk[i][nf] = (f32x4){0.f,0.f,0.f,0.f};
  #pragma unroll
  for (int j = 0; j < 4; j++)
    #pragma unroll
    for (int nf = 0; nf < 2; nf++) av[j][nf] = (f32x4){0.f,0.f,0.f,0.f};

  #pragma unroll 2
  for (int kc = 0; kc < 8; kc++){
    short8 bfr[2];
    #pragma unroll
    for (int nf = 0; nf < 2; nf++)
      bfr[nf] = *(const short8*)(Tb + (size_t)(n0 + nf * 16 + l15) * 256 + kc * 32 + g * 8);
    short8 aq[2];
    #pragma unroll
    for (int i = 0; i < 2; i++)
      aq[i] = *(const short8*)(Wbf + (size_t)((2 * w + i) * 16 + l15) * 256 + kc * 32 + g * 8);
    short8 afv[4];
    #pragma unroll
    for (int j = 0; j < 4; j++)
      afv[j] = *(const short8*)(Wbf + (size_t)(128 + (4 * w + j) * 16 + l15) * 256 + kc * 32 + g * 8);
    #pragma unroll
    for (int i = 0; i < 2; i++)
      #pragma unroll
      for (int nf = 0; nf < 2; nf++)
        aqk[i][nf] = __builtin_amdgcn_mfma_f32_16x16x32_bf16(aq[i], bfr[nf], aqk[i][nf], 0, 0, 0);
    #pragma unroll
    for (int j = 0; j < 4; j++)
      #pragma unroll
      for (int nf = 0; nf < 2; nf++)
        av[j][nf] = __builtin_amdgcn_mfma_f32_16x16x32_bf16(bfr[nf], afv[j], av[j][nf], 0, 0, 0);
  }
  unsigned short* qk = (w < 2) ? qo : ko;
  #pragma unroll
  for (int i = 0; i < 2; i++)
    #pragma unroll
    for (int nf = 0; nf < 2; nf++){
      int n = n0 + nf * 16 + l15;
      int cbase = (w & 1) * 32 + i * 16 + g * 4;
      short4v pk;
      #pragma unroll
      for (int r = 0; r < 4; r++) pk[r] = (short)f2bf(aqk[i][nf][r]);
      *(short4v*)(qk + ((size_t)b * 2048 + n) * 64 + cbase) = pk;
    }
  #pragma unroll
  for (int j = 0; j < 4; j++)
    #pragma unroll
    for (int nf = 0; nf < 2; nf++){
      int o = (4 * w + j) * 16 + l15;
      int nb2 = n0 + nf * 16 + g * 4;
      short4v pv;
      #pragma unroll
      for (int r = 0; r < 4; r++) pv[r] = (short)f2bf(av[j][nf][r]);
      *(short4v*)(vt + ((size_t)b * 256 + o) * 2048 + nb2) = pv;
    }
}

// ---------------- K3: params[b][r] = pooled[b] . ctrl_w[r] + ctrl_b[r] -----------
__global__ __launch_bounds__(256) void k3_params(const unsigned* __restrict__ pooledEnc,
    const float* __restrict__ cw, const float* __restrict__ cb,
    float* __restrict__ params){
  __shared__ float P[8 * 256];
  const int tid = threadIdx.x;
  for (int i = tid; i < 2048; i += 256) P[i] = fdec(pooledEnc[i]);
  __syncthreads();
  const int w = tid >> 6, lane = tid & 63;
  const int r = blockIdx.x * 4 + w;
  if (r >= 8385) return;
  float4 c4 = ((const float4*)(cw + (size_t)r * 256))[lane];
  float bias = cb[r];
  #pragma unroll
  for (int b = 0; b < 8; b++){
    const float* pbp = P + b * 256 + lane * 4;
    float s = c4.x * pbp[0] + c4.y * pbp[1] + c4.z * pbp[2] + c4.w * pbp[3];
    #pragma unroll
    for (int d = 1; d < 64; d <<= 1) s += __shfl_xor(s, d);
    if (lane == 0) params[b * 8385 + r] = s + bias;
  }
}

// ---------------- kFA: fused attention = kB with P-staging replaced by QK --------
// 512 WGs x 256 thr (b = wg&7 XCD-local; rest: oh = o-half, qt -> 64 q-rows).
// LDS: Pl 8KB [64 q][128B swz] + Vl 16KB [128 o][128B swz]. Per 64-m chunk:
// [K frags + V stage loads + QK MFMA (regs)] -> barrier -> [exp->Pl + Vl
// writes] -> barrier -> [kB frag reads + 16 MFMA PV]. Wave w owns q-rows
// w*16.. (QK+rowsum) and o-slice w*32.. (PV). Q frags hoisted.
__global__ __launch_bounds__(256, 2) void kFA(
    const unsigned short* __restrict__ Qg, const unsigned short* __restrict__ Kg,
    const unsigned short* __restrict__ Vt, unsigned* __restrict__ tmaxe){
  const int wg = blockIdx.x;
  const int b = wg & 7;
  const int rest = wg >> 3;
  const int oh = rest & 1;
  const int q0 = (rest >> 1) * 64;
  const int tid = threadIdx.x, lane = tid & 63, w = tid >> 6;
  const int l15 = lane & 15, g = lane >> 4;
  __shared__ __align__(16) unsigned char smem[24576];    // Pl 8KB | Vl 16KB
  unsigned char* Pl = smem;
  unsigned char* Vl = smem + 8192;
  __shared__ float sden[64];

  const unsigned short* Qb = Qg + (size_t)b * 2048 * 64;
  const unsigned short* Kb = Kg + (size_t)b * 2048 * 64;
  const unsigned short* Vb = Vt + ((size_t)b * 256 + oh * 128) * 2048;

  // hoisted Q frags: this wave's 16 q-rows [q0 + w*16, +16)
  short8 qf[2];
  #pragma unroll
  for (int kc = 0; kc < 2; kc++)
    qf[kc] = *(const short8*)(Qb + (size_t)(q0 + w * 16 + l15) * 64 + kc * 32 + g * 8);

  float ps[4] = {0.f, 0.f, 0.f, 0.f};
  f32x4 acc[4][2];
  #pragma unroll
  for (int ni = 0; ni < 4; ni++)
    #pragma unroll
    for (int oi = 0; oi < 2; oi++) acc[ni][oi] = (f32x4){0.f,0.f,0.f,0.f};

  for (int t = 0; t < 32; ++t){
    const int mb = t * 64;
    // K frags for this chunk (kA's proven pattern)
    short8 kf[4][2];
    #pragma unroll
    for (int mi = 0; mi < 4; mi++)
      #pragma unroll
      for (int kc = 0; kc < 2; kc++)
        kf[mi][kc] = *(const short8*)(Kb + (size_t)(mb + mi * 16 + l15) * 64 + kc * 32 + g * 8);
    // V-half stage loads (kB's proven coalesced pattern): 16KB, 4 x 4KB
    short8 vstg[4];
    #pragma unroll
    for (int k = 0; k < 4; k++){
      int d = k * 4096 + tid * 16;
      int row = d >> 7;
      vstg[k] = *(const short8*)(Vb + (size_t)row * 2048 + mb + ((d & 127) >> 1));
    }
    // QK: sa[mi] D-tile: q = q0 + w*16 + g*4 + r, m = mb + mi*16 + l15
    f32x4 sa[4];
    #pragma unroll
    for (int mi = 0; mi < 4; mi++) sa[mi] = (f32x4){0.f,0.f,0.f,0.f};
    #pragma unroll
    for (int mi = 0; mi < 4; mi++)
      #pragma unroll
      for (int kc = 0; kc < 2; kc++)
        sa[mi] = __builtin_amdgcn_mfma_f32_16x16x32_bf16(qf[kc], kf[mi][kc], sa[mi], 0, 0, 0);
    __syncthreads();                                     // prev PV reads done
    // exp -> Pl (swizzled); row-sum partials (wave-local rows)
    #pragma unroll
    for (int mi = 0; mi < 4; mi++)
      #pragma unroll
      for (int r = 0; r < 4; r++){
        float p = __expf(sa[mi][r]);
        ps[r] += p;
        int row = w * 16 + g * 4 + r;                    // q-local
        int col = mi * 16 + l15;                         // m-local
        *(unsigned short*)(Pl + ((unsigned)(row * 128 + col * 2) ^ ((unsigned)(row & 7) << 4))) = f2bf(p);
      }
    // V staged regs -> Vl (swizzled b128, kB pattern)
    #pragma unroll
    for (int k = 0; k < 4; k++){
      int d = k * 4096 + tid * 16;
      int row = d >> 7;
      *(short8*)(Vl + (d ^ ((row & 7) << 4))) = vstg[k];
    }
    __syncthreads();                                     // staging + P visible
    // PV (kB's exact frag reads): af rows = q-local, bf rows = o-local slice
    short8 af[4][2], bf[2][2];
    #pragma unroll
    for (int ni = 0; ni < 4; ni++)
      #pragma unroll
      for (int kc = 0; kc < 2; kc++){
        int row = ni * 16 + l15;
        af[ni][kc] = *(const short8*)(Pl + ((row * 128 + kc * 64 + g * 16) ^ ((row & 7) << 4)));
      }
    #pragma unroll
    for (int oi = 0; oi < 2; oi++)
      #pragma unroll
      for (int kc = 0; kc < 2; kc++){
        int row = w * 32 + oi * 16 + l15;
        bf[oi][kc] = *(const short8*)(Vl + ((row * 128 + kc * 64 + g * 16) ^ ((row & 7) << 4)));
      }
    #pragma unroll
    for (int ni = 0; ni < 4; ni++)
      #pragma unroll
      for (int oi = 0; oi < 2; oi++)
        #pragma unroll
        for (int kc = 0; kc < 2; kc++)
          acc[ni][oi] = __builtin_amdgcn_mfma_f32_16x16x32_bf16(af[ni][kc], bf[oi][kc], acc[ni][oi], 0, 0, 0);
  }
  // denominators: wave-local 16-lane-group reduce, publish via LDS
  #pragma unroll
  for (int r = 0; r < 4; r++){
    float s = ps[r];
    s += __shfl_xor(s, 1); s += __shfl_xor(s, 2);
    s += __shfl_xor(s, 4); s += __shfl_xor(s, 8);
    if (l15 == 0) sden[w * 16 + g * 4 + r] = s;
  }
  __syncthreads();
  float inv[4][4];
  #pragma unroll
  for (int ni = 0; ni < 4; ni++)
    #pragma unroll
    for (int r = 0; r < 4; r++)
      inv[ni][r] = 1.0f / sden[ni * 16 + g * 4 + r];
  #pragma unroll
  for (int oi = 0; oi < 2; oi++){
    float cm = -1e30f;
    #pragma unroll
    for (int ni = 0; ni < 4; ni++)
      #pragma unroll
      for (int r = 0; r < 4; r++)
        cm = fmaxf(cm, acc[ni][oi][r] * inv[ni][r]);
    cm = fmaxf(cm, __shfl_xor(cm, 16));
    cm = fmaxf(cm, __shfl_xor(cm, 32));
    if (lane < 16)
      atomicMax(&tmaxe[b * 256 + oh * 128 + w * 32 + oi * 16 + lane], fenc(cm));
  }
}

// ---------------- K5: W_eff = P0 + P1*t + P2 (bf16); bias_eff; w0/w1 -> bf16 -----
__global__ __launch_bounds__(256) void k5_weff(const float* __restrict__ proj_w,
    const float* __restrict__ proj_b, const unsigned* __restrict__ tmaxe,
    const float* __restrict__ params, unsigned short* __restrict__ weff,
    float* __restrict__ beff, unsigned short* __restrict__ w0b,
    unsigned short* __restrict__ w1b){
  const int b = blockIdx.y, o = blockIdx.x;
  const int c = threadIdx.x;                  // 256
  float t = fdec(tmaxe[b * 256 + c]);
  float p0 = proj_w[o * 768 + c];
  float p1 = proj_w[o * 768 + 256 + c];
  float p2 = proj_w[o * 768 + 512 + c];
  weff[((size_t)b * 64 + o) * 256 + c] = f2bf(p0 + p1 * t + p2);
  float s = p0 * t;
  #pragma unroll
  for (int d = 1; d < 64; d <<= 1) s += __shfl_xor(s, d);
  __shared__ float sm[4];
  if ((c & 63) == 0) sm[c >> 6] = s;
  __syncthreads();
  if (c == 0) beff[b * 64 + o] = proj_b[o] - (sm[0] + sm[1] + sm[2] + sm[3]);
  if (c < 64)        w0b[((size_t)b * 64 + o) * 64 + c] = f2bf(params[b * 8385 + o * 64 + c]);
  else if (c < 128)  w1b[((size_t)b * 64 + o) * 64 + (c - 64)] = f2bf(params[b * 8385 + 4096 + o * 64 + (c - 64)]);
}

// ---------------- K6: fused scene pipeline (scene read exactly once) -------------
__global__ __launch_bounds__(512) void k6_main(const float* __restrict__ Sg,
    const unsigned short* __restrict__ weff, const float* __restrict__ beff,
    const unsigned short* __restrict__ w0b, const unsigned short* __restrict__ w1b,
    const float* __restrict__ params, float* __restrict__ out){
  const int b = blockIdx.y, nt = blockIdx.x;
  const int n0 = nt * 256;
  const int tid = threadIdx.x, lane = tid & 63, w = tid >> 6;
  const int l15 = lane & 15, g = lane >> 4;
  __shared__ __align__(16) unsigned char smem[65536];
  unsigned short* H0 = (unsigned short*)smem;            // [n][64] XOR-swizzled, 32 KB
  unsigned char*  Ub = smem + 32768;                     // Bs32 (16KB) then H1 (32KB)
  unsigned short* H1 = (unsigned short*)Ub;

  const float* Sb = Sg + (size_t)b * 256 * 16384;
  const unsigned short* We = weff + (size_t)b * 64 * 256;
  f32x4 a0[4][2];
  #pragma unroll
  for (int mi = 0; mi < 4; mi++)
    #pragma unroll
    for (int ni = 0; ni < 2; ni++) a0[mi][ni] = (f32x4){0.f,0.f,0.f,0.f};

  const int scc = tid & 31;                   // c row within k-tile
  const int snb = (tid >> 5) * 16;            // 16 n per thread
  for (int k0 = 0; k0 < 256; k0 += 32){
    const float* src = Sb + (size_t)(k0 + scc) * 16384 + n0 + snb;
    float4 v0 = ((const float4*)src)[0];
    float4 v1 = ((const float4*)src)[1];
    float4 v2 = ((const float4*)src)[2];
    float4 v3 = ((const float4*)src)[3];
    float vals[16] = {v0.x,v0.y,v0.z,v0.w, v1.x,v1.y,v1.z,v1.w,
                      v2.x,v2.y,v2.z,v2.w, v3.x,v3.y,v3.z,v3.w};
    #pragma unroll
    for (int j = 0; j < 16; j++){
      int n = snb + j;
      unsigned byteo = ((unsigned)(n * 64 + scc * 2)) ^ ((unsigned)((n >> 1) & 3) << 4);
      *(unsigned short*)(Ub + byteo) = f2bf(vals[j]);
    }
    __syncthreads();
    short8 bf0[2];
    #pragma unroll
    for (int ni = 0; ni < 2; ni++){
      int n = w * 32 + ni * 16 + l15;
      bf0[ni] = *(const short8*)(Ub + (((unsigned)(n * 64 + g * 16)) ^ ((unsigned)((n >> 1) & 3) << 4)));
    }
    #pragma unroll
    for (int mi = 0; mi < 4; mi++){
      short8 af = *(const short8*)(We + (mi * 16 + l15) * 256 + k0 + g * 8);
      #pragma unroll
      for (int ni = 0; ni < 2; ni++)
        a0[mi][ni] = __builtin_amdgcn_mfma_f32_16x16x32_bf16(af, bf0[ni], a0[mi][ni], 0, 0, 0);
    }
    __syncthreads();
  }
  const float* be = beff + b * 64;
  #pragma unroll
  for (int mi = 0; mi < 4; mi++)
    #pragma unroll
    for (int ni = 0; ni < 2; ni++){
      int n = w * 32 + ni * 16 + l15;
      unsigned base = ((unsigned)(n * 128 + mi * 32 + g * 8)) ^ ((unsigned)((n & 7) << 4));
      unsigned short hh[4];
      #pragma unroll
      for (int r = 0; r < 4; r++){
        int o = mi * 16 + g * 4 + r;
        hh[r] = f2bf(fmaxf(a0[mi][ni][r] + be[o], 0.f));
      }
      *(unsigned*)((unsigned char*)H0 + base)     = (unsigned)hh[0] | ((unsigned)hh[1] << 16);
      *(unsigned*)((unsigned char*)H0 + base + 4) = (unsigned)hh[2] | ((unsigned)hh[3] << 16);
    }
  __syncthreads();
  f32x4 a1[4][2];
  #pragma unroll
  for (int mi = 0; mi < 4; mi++)
    #pragma unroll
    for (int ni = 0; ni < 2; ni++) a1[mi][ni] = (f32x4){0.f,0.f,0.f,0.f};
  const unsigned short* W0 = w0b + (size_t)b * 4096;
  #pragma unroll
  for (int ks = 0; ks < 2; ks++){
    short8 bfh[2];
    #pragma unroll
    for (int ni = 0; ni < 2; ni++){
      int n = w * 32 + ni * 16 + l15;
      unsigned off = ((unsigned)(n * 128 + ks * 64 + g * 16)) ^ ((unsigned)((n & 7) << 4));
      bfh[ni] = *(const short8*)((unsigned char*)H0 + off);
    }
    #pragma unroll
    for (int mi = 0; mi < 4; mi++){
      short8 af = *(const short8*)(W0 + (mi * 16 + l15) * 64 + ks * 32 + g * 8);
      #pragma unroll
      for (int ni = 0; ni < 2; ni++)
        a1[mi][ni] = __builtin_amdgcn_mfma_f32_16x16x32_bf16(af, bfh[ni], a1[mi][ni], 0, 0, 0);
    }
  }
  const float* pp = params + (size_t)b * 8385;
  const float* b0p = pp + 8256;
  #pragma unroll
  for (int mi = 0; mi < 4; mi++)
    #pragma unroll
    for (int ni = 0; ni < 2; ni++){
      int n = w * 32 + ni * 16 + l15;
      unsigned base = ((unsigned)(n * 128 + mi * 32 + g * 8)) ^ ((unsigned)((n & 7) << 4));
      unsigned short hh[4];
      #pragma unroll
      for (int r = 0; r < 4; r++){
        int o = mi * 16 + g * 4 + r;
        hh[r] = f2bf(fmaxf(a1[mi][ni][r] + b0p[o], 0.f));
      }
      *(unsigned*)((unsigned char*)H1 + base)     = (unsigned)hh[0] | ((unsigned)hh[1] << 16);
      *(unsigned*)((unsigned char*)H1 + base + 4) = (unsigned)hh[2] | ((unsigned)hh[3] << 16);
    }
  __syncthreads();
  f32x4 a2[4][2];
  #pragma unroll
  for (int mi = 0; mi < 4; mi++)
    #pragma unroll
    for (int ni = 0; ni < 2; ni++) a2[mi][ni] = (f32x4){0.f,0.f,0.f,0.f};
  const unsigned short* W1 = w1b + (size_t)b * 4096;
  #pragma unroll
  for (int ks = 0; ks < 2; ks++){
    short8 bfh[2];
    #pragma unroll
    for (int ni = 0; ni < 2; ni++){
      int n = w * 32 + ni * 16 + l15;
      unsigned off = ((unsigned)(n * 128 + ks * 64 + g * 16)) ^ ((unsigned)((n & 7) << 4));
      bfh[ni] = *(const short8*)((unsigned char*)H1 + off);
    }
    #pragma unroll
    for (int mi = 0; mi < 4; mi++){
      short8 af = *(const short8*)(W1 + (mi * 16 + l15) * 64 + ks * 32 + g * 8);
      #pragma unroll
      for (int ni = 0; ni < 2; ni++)
        a2[mi][ni] = __builtin_amdgcn_mfma_f32_16x16x32_bf16(af, bfh[ni], a2[mi][ni], 0, 0, 0);
    }
  }
  const float* b1p = pp + 8320;
  const float* w2p = pp + 8192;
  float b2v = pp[8384];
  #pragma unroll
  for (int ni = 0; ni < 2; ni++){
    float t = 0.f;
    #pragma unroll
    for (int mi = 0; mi < 4; mi++)
      #pragma unroll
      for (int r = 0; r < 4; r++){
        int o = mi * 16 + g * 4 + r;
        t += w2p[o] * fmaxf(a2[mi][ni][r] + b1p[o], 0.f);
      }
    t += __shfl_xor(t, 16);
    t += __shfl_xor(t, 32);
    if (lane < 16)
      out[(size_t)b * 16384 + n0 + w * 32 + ni * 16 + l15] = t + b2v;
  }
}

extern "C" void kernel_launch(void* const* d_in, const int* in_sizes, int n_in,
                              void* d_out, int out_size, void* d_ws, size_t ws_size,
                              hipStream_t stream){
  const float* scene = (const float*)d_in[0];
  const float* tmpl  = (const float*)d_in[1];
  const float* qw    = (const float*)d_in[2];
  const float* kw    = (const float*)d_in[3];
  const float* vw    = (const float*)d_in[4];
  const float* pw    = (const float*)d_in[5];
  const float* pb    = (const float*)d_in[6];
  const float* cw    = (const float*)d_in[7];
  const float* cb    = (const float*)d_in[8];
  float* out = (float*)d_out;
  char* ws = (char*)d_ws;

  unsigned short* Q      = (unsigned short*)(ws + 0);                    // 2 MB
  unsigned short* K      = (unsigned short*)(ws + (2u << 20));           // 2 MB
  unsigned short* V      = (unsigned short*)(ws + (4u << 20));           // 8 MB
  unsigned*       pooledEnc = (unsigned*)(ws + (12u << 20));             // 8 KB
  unsigned*       tmaxe  = (unsigned*)(ws + (12u << 20) + 8192);         // 8 KB
  float*          params = (float*)(ws + (12u << 20) + 16384);           // 268 KB
  unsigned short* w0b    = (unsigned short*)(ws + (13u << 20));          // 64 KB
  unsigned short* w1b    = (unsigned short*)(ws + (13u << 20) + 65536);  // 64 KB
  unsigned short* weff   = (unsigned short*)(ws + (13u << 20) + 131072); // 256 KB
  float*          beff   = (float*)(ws + (13u << 20) + 131072 + 262144); // 2 KB
  unsigned short* Wbf    = (unsigned short*)(ws + (14u << 20) + 131072); // 192 KB
  unsigned short* Tt     = (unsigned short*)(ws + (16u << 20));          // 8 MB

  k0w<<<dim3(96), dim3(256), 0, stream>>>(qw, kw, vw, Wbf, tmaxe, pooledEnc);
  k0_tt<<<dim3(8, 16, 8), dim3(256), 0, stream>>>(tmpl, Tt, pooledEnc);
  k2_qkv<<<dim3(512), dim3(256), 0, stream>>>(Wbf, Tt, Q, K, V);
  k3_params<<<dim3(2097), dim3(256), 0, stream>>>(pooledEnc, cw, cb, params);
  kFA<<<dim3(512), dim3(256), 0, stream>>>(Q, K, V, tmaxe);
  k5_weff<<<dim3(64, 8), dim3(256), 0, stream>>>(pw, pb, tmaxe, params, weff, beff, w0b, w1b);
  k6_main<<<dim3(64, 8), dim3(512), 0, stream>>>(scene, weff, beff, w0b, w1b, params, out);
}

// Round 11
// 151.531 us; speedup vs baseline: 1.1602x; 1.1602x over previous
//
#include <hip/hip_runtime.h>

// DynamicConvolution fused pipeline for MI355X (gfx950).
// R11 (base = R9, best 153.0): kB rebuilt as single-barrier double-buffered
// pipeline (stage loads for t+1 issued before PV of t -> L2 latency hidden
// under MFMA; 48KB LDS, 2 WG/CU). kA mt-loop unrolled (K-frag hoisting).
// k3 merged into k2's launch (independent siblings, one less gap).
// Stages: k0w -> k0_tt -> k23 qkv+params -> kA exp(QK^T) -> kB PV+tmax ->
//         k5 W_eff -> k6 fused scene MLP.

typedef __attribute__((ext_vector_type(8))) short short8;
typedef __attribute__((ext_vector_type(4))) short short4v;
typedef __attribute__((ext_vector_type(4))) float f32x4;

__device__ __forceinline__ unsigned short f2bf(float f){
  unsigned u = __float_as_uint(f);
  u += 0x7FFFu + ((u >> 16) & 1u);           // round-to-nearest-even
  return (unsigned short)(u >> 16);
}
// monotone float<->uint for atomicMax on floats (incl. negatives)
__device__ __forceinline__ unsigned fenc(float f){
  unsigned u = __float_as_uint(f);
  return (u & 0x80000000u) ? ~u : (u | 0x80000000u);
}
__device__ __forceinline__ float fdec(unsigned k){
  unsigned u = (k & 0x80000000u) ? (k & 0x7FFFFFFFu) : ~k;
  return __uint_as_float(u);
}

// ---------------- k0w: Wbf[384][256] bf16 (q*0.125 folded); init tmaxe/pooledEnc -
__global__ __launch_bounds__(256) void k0w(const float* __restrict__ qw,
    const float* __restrict__ kw, const float* __restrict__ vw,
    unsigned short* __restrict__ Wbf, unsigned* __restrict__ tmaxe,
    unsigned* __restrict__ pooledEnc){
  if (blockIdx.x == 0){
    const unsigned ninf = fenc(-3.0e38f);
    for (int i = threadIdx.x; i < 2048; i += 256){
      tmaxe[i] = 0u;                          // floor for encoded O-max
      pooledEnc[i] = ninf;                    // true -inf floor for pooled max
    }
  }
  const int e = (blockIdx.x * 256 + threadIdx.x) * 4;   // 96 WGs * 1024 = 98304
  const int row = e >> 8, c = e & 255;
  const float* src;
  float scl = 1.0f;
  if (row < 64){ src = qw + row * 256 + c; scl = 0.125f; }
  else if (row < 128){ src = kw + (row - 64) * 256 + c; }
  else { src = vw + (row - 128) * 256 + c; }
  float4 v = *(const float4*)src;
  short4v o;
  o[0] = (short)f2bf(v.x * scl); o[1] = (short)f2bf(v.y * scl);
  o[2] = (short)f2bf(v.z * scl); o[3] = (short)f2bf(v.w * scl);
  *(short4v*)(Wbf + e) = o;
}

// ---------------- k0_tt: Tt[b][n][c] = bf16(T[b][c][n]); pooled max fold ---------
__global__ __launch_bounds__(256) void k0_tt(const float* __restrict__ T,
    unsigned short* __restrict__ Tt, unsigned* __restrict__ pooledEnc){
  const int b = blockIdx.x, nt = blockIdx.y, ct = blockIdx.z;
  const int n0 = nt * 128, c0 = ct * 32;
  const int tid = threadIdx.x;
  __shared__ float Ls[32][129];
  const int cr = tid >> 3, nq = tid & 7;      // 32 c-rows x 8 n-chunks(16 f32)
  const float* src = T + ((size_t)b * 256 + c0 + cr) * 2048 + n0 + nq * 16;
  float4 v0 = ((const float4*)src)[0];
  float4 v1 = ((const float4*)src)[1];
  float4 v2 = ((const float4*)src)[2];
  float4 v3 = ((const float4*)src)[3];
  float mx = fmaxf(fmaxf(fmaxf(v0.x, v0.y), fmaxf(v0.z, v0.w)),
                   fmaxf(fmaxf(v1.x, v1.y), fmaxf(v1.z, v1.w)));
  mx = fmaxf(mx, fmaxf(fmaxf(fmaxf(v2.x, v2.y), fmaxf(v2.z, v2.w)),
                       fmaxf(fmaxf(v3.x, v3.y), fmaxf(v3.z, v3.w))));
  mx = fmaxf(mx, __shfl_xor(mx, 1));
  mx = fmaxf(mx, __shfl_xor(mx, 2));
  mx = fmaxf(mx, __shfl_xor(mx, 4));
  if (nq == 0) atomicMax(&pooledEnc[b * 256 + c0 + cr], fenc(mx));
  float* lr = &Ls[cr][nq * 16];
  *(float4*)lr = v0; *(float4*)(lr + 4) = v1;
  *(float4*)(lr + 8) = v2; *(float4*)(lr + 12) = v3;
  __syncthreads();
  const int nr = tid >> 1, ch = tid & 1;      // 128 n-rows x 2 c-halves(16)
  unsigned short ob[16];
  #pragma unroll
  for (int j = 0; j < 16; j++) ob[j] = f2bf(Ls[ch * 16 + j][nr]);
  unsigned short* dst = Tt + ((size_t)b * 2048 + n0 + nr) * 256 + c0 + ch * 16;
  *(short8*)dst = *(short8*)&ob[0];
  *(short8*)(dst + 8) = *(short8*)&ob[8];
}

// ---------------- k23: fused k2 (QKV gemm, wg<512) + k3 (params gemv) ------------
__global__ __launch_bounds__(256) void k23_qkv_params(
    const unsigned short* __restrict__ Wbf, const unsigned short* __restrict__ Tt,
    unsigned short* __restrict__ qo, unsigned short* __restrict__ ko,
    unsigned short* __restrict__ vt,
    const unsigned* __restrict__ pooledEnc, const float* __restrict__ cw,
    const float* __restrict__ cb, float* __restrict__ params){
  const int wg = blockIdx.x;
  const int tid = threadIdx.x, lane = tid & 63, w = tid >> 6;
  if (wg >= 512){
    // ---- k3 body: params[b][r] = pooled[b].cw[r] + cb[r]
    __shared__ float P[8 * 256];
    for (int i = tid; i < 2048; i += 256) P[i] = fdec(pooledEnc[i]);
    __syncthreads();
    const int r = (wg - 512) * 4 + w;
    if (r >= 8385) return;
    float4 c4 = ((const float4*)(cw + (size_t)r * 256))[lane];
    float bias = cb[r];
    #pragma unroll
    for (int b = 0; b < 8; b++){
      const float* pbp = P + b * 256 + lane * 4;
      float s = c4.x * pbp[0] + c4.y * pbp[1] + c4.z * pbp[2] + c4.w * pbp[3];
      #pragma unroll
      for (int d = 1; d < 64; d <<= 1) s += __shfl_xor(s, d);
      if (lane == 0) params[b * 8385 + r] = s + bias;
    }
    return;
  }
  // ---- k2 body (R5-proven): no LDS, direct global frags
  const int b = wg & 7, nt = wg >> 3;
  const int n0 = nt * 32;
  const int l15 = lane & 15, g = lane >> 4;
  const unsigned short* Tb = Tt + (size_t)b * 2048 * 256;

  f32x4 aqk[2][2], av[4][2];
  #pragma unroll
  for (int i = 0; i < 2; i++)
    #pragma unroll
    for (int nf = 0; nf < 2; nf++) aqk[i][nf] = (f32x4){0.f,0.f,0.f,0.f};
  #pragma unroll
  for (int j = 0; j < 4; j++)
    #pragma unroll
    for (int nf = 0; nf < 2; nf++) av[j][nf] = (f32x4){0.f,0.f,0.f,0.f};

  #pragma unroll 2
  for (int kc = 0; kc < 8; kc++){
    short8 bfr[2];
    #pragma unroll
    for (int nf = 0; nf < 2; nf++)
      bfr[nf] = *(const short8*)(Tb + (size_t)(n0 + nf * 16 + l15) * 256 + kc * 32 + g * 8);
    short8 aq[2];
    #pragma unroll
    for (int i = 0; i < 2; i++)
      aq[i] = *(const short8*)(Wbf + (size_t)((2 * w + i) * 16 + l15) * 256 + kc * 32 + g * 8);
    short8 afv[4];
    #pragma unroll
    for (int j = 0; j < 4; j++)
      afv[j] = *(const short8*)(Wbf + (size_t)(128 + (4 * w + j) * 16 + l15) * 256 + kc * 32 + g * 8);
    #pragma unroll
    for (int i = 0; i < 2; i++)
      #pragma unroll
      for (int nf = 0; nf < 2; nf++)
        aqk[i][nf] = __builtin_amdgcn_mfma_f32_16x16x32_bf16(aq[i], bfr[nf], aqk[i][nf], 0, 0, 0);
    #pragma unroll
    for (int j = 0; j < 4; j++)
      #pragma unroll
      for (int nf = 0; nf < 2; nf++)
        av[j][nf] = __builtin_amdgcn_mfma_f32_16x16x32_bf16(bfr[nf], afv[j], av[j][nf], 0, 0, 0);
  }
  unsigned short* qk = (w < 2) ? qo : ko;
  #pragma unroll
  for (int i = 0; i < 2; i++)
    #pragma unroll
    for (int nf = 0; nf < 2; nf++){
      int n = n0 + nf * 16 + l15;
      int cbase = (w & 1) * 32 + i * 16 + g * 4;
      short4v pk;
      #pragma unroll
      for (int r = 0; r < 4; r++) pk[r] = (short)f2bf(aqk[i][nf][r]);
      *(short4v*)(qk + ((size_t)b * 2048 + n) * 64 + cbase) = pk;
    }
  #pragma unroll
  for (int j = 0; j < 4; j++)
    #pragma unroll
    for (int nf = 0; nf < 2; nf++){
      int o = (4 * w + j) * 16 + l15;
      int nb2 = n0 + nf * 16 + g * 4;
      short4v pv;
      #pragma unroll
      for (int r = 0; r < 4; r++) pv[r] = (short)f2bf(av[j][nf][r]);
      *(short4v*)(vt + ((size_t)b * 256 + o) * 2048 + nb2) = pv;
    }
}

// ---------------- kA: P (tiled) = exp(S); 512 thr, q-tile 32, unrolled mt --------
__global__ __launch_bounds__(512, 4) void kA_scores(
    const unsigned short* __restrict__ Qg, const unsigned short* __restrict__ Kg,
    unsigned short* __restrict__ Pg, float* __restrict__ sbuf,
    int b0, int bshift){
  const int wg = blockIdx.x;
  const int bmask = (1 << bshift) - 1;
  const int b = b0 + (wg & bmask);
  const int q0 = (wg >> bshift) * 32;
  const int qb0 = (wg >> bshift) * 2;
  const int tid = threadIdx.x, lane = tid & 63, w = tid >> 6;
  const int l15 = lane & 15, g = lane >> 4;
  __shared__ float wsum[32][8];
  const unsigned short* Qb = Qg + (size_t)b * 2048 * 64;
  const unsigned short* Kb = Kg + (size_t)b * 2048 * 64;
  unsigned short* Pb = Pg + (size_t)(wg & bmask) * 2048 * 2048;

  short8 qf[2][2];
  #pragma unroll
  for (int qi = 0; qi < 2; qi++)
    #pragma unroll
    for (int kc = 0; kc < 2; kc++)
      qf[qi][kc] = *(const short8*)(Qb + (size_t)(q0 + qi * 16 + l15) * 64 + kc * 32 + g * 8);

  float ps[2][4];
  #pragma unroll
  for (int qi = 0; qi < 2; qi++)
    #pragma unroll
    for (int r = 0; r < 4; r++) ps[qi][r] = 0.f;

  const int wm0 = w * 256;
  #pragma unroll
  for (int mt = 0; mt < 4; ++mt){
    const int mb = wm0 + mt * 64;
    short8 kf[4][2];
    #pragma unroll
    for (int mi = 0; mi < 4; mi++)
      #pragma unroll
      for (int kc = 0; kc < 2; kc++)
        kf[mi][kc] = *(const short8*)(Kb + (size_t)(mb + mi * 16 + l15) * 64 + kc * 32 + g * 8);
    #pragma unroll
    for (int qi = 0; qi < 2; qi++){
      f32x4 sa[4];
      #pragma unroll
      for (int mi = 0; mi < 4; mi++) sa[mi] = (f32x4){0.f,0.f,0.f,0.f};
      #pragma unroll
      for (int mi = 0; mi < 4; mi++)
        #pragma unroll
        for (int kc = 0; kc < 2; kc++)
          sa[mi] = __builtin_amdgcn_mfma_f32_16x16x32_bf16(qf[qi][kc], kf[mi][kc], sa[mi], 0, 0, 0);
      #pragma unroll
      for (int mi = 0; mi < 4; mi++){
        short4v pk;
        #pragma unroll
        for (int r = 0; r < 4; r++){
          float p = __expf(sa[mi][r]);
          ps[qi][r] += p;
          pk[r] = (short)f2bf(p);
        }
        *(short4v*)(Pb + ((size_t)((qb0 + qi) * 128 + w * 16 + mt * 4 + mi)) * 256 + lane * 4) = pk;
      }
    }
  }
  #pragma unroll
  for (int qi = 0; qi < 2; qi++)
    #pragma unroll
    for (int r = 0; r < 4; r++){
      float t = ps[qi][r];
      t += __shfl_xor(t, 1); t += __shfl_xor(t, 2);
      t += __shfl_xor(t, 4); t += __shfl_xor(t, 8);
      if (l15 == 0) wsum[qi * 16 + g * 4 + r][w] = t;
    }
  __syncthreads();
  if (tid < 32){
    float t = 0.f;
    #pragma unroll
    for (int i = 0; i < 8; i++) t += wsum[tid][i];
    sbuf[(size_t)b * 2048 + q0 + tid] = t;
  }
}

// ---------------- kB v3: O = P@V^T, dbuf single-barrier pipeline -----------------
// grid 64*nb (b = wg&bmask; rest: oh = o-half, nt -> 64 n-rows). LDS dbuf 2x24KB
// (P 8KB + V-half 16KB, swizzled). Iter t: issue loads(t+1) -> PV on buf[t&1]
// -> write regs(t+1) -> buf[(t+1)&1] -> ONE barrier. L2 latency of the stage
// loads hides under the 12 frag reads + 16 MFMA.
__global__ __launch_bounds__(256, 2) void kB_pv(
    const unsigned short* __restrict__ Pg, const unsigned short* __restrict__ Vt,
    const float* __restrict__ sbuf, unsigned* __restrict__ tmaxe,
    int b0, int bshift){
  const int wg = blockIdx.x;
  const int bmask = (1 << bshift) - 1;
  const int b = b0 + (wg & bmask);
  const int rest = wg >> bshift;
  const int oh = rest & 1;
  const int n0 = (rest >> 1) * 64;
  const int qb0 = n0 >> 4;
  const int tid = threadIdx.x, lane = tid & 63, w = tid >> 6;
  const int l15 = lane & 15, g = lane >> 4;
  __shared__ __align__(16) unsigned char smem[2][24576];  // dbuf: Pl 8KB | Vl 16KB

  const unsigned short* Pb = Pg + (size_t)(wg & bmask) * 2048 * 2048;
  const unsigned short* Vb = Vt + ((size_t)b * 256 + oh * 128) * 2048;

  f32x4 acc[4][2];
  #pragma unroll
  for (int ni = 0; ni < 4; ni++)
    #pragma unroll
    for (int oi = 0; oi < 2; oi++) acc[ni][oi] = (f32x4){0.f,0.f,0.f,0.f};

  // staging helpers (R6/R9-proven addressing), parameterized by m0 and buffer
  short8 stg[6];
  auto LOADS = [&](int m0){
    const int mb0 = m0 >> 4;
    #pragma unroll
    for (int k = 0; k < 6; k++){
      int d = k * 4096 + tid * 16;
      if (k < 2){                                        // P tiles: 16 x 512B
        int ti = d >> 9;
        int qi = ti >> 2, mi = ti & 3;
        stg[k] = *(const short8*)(Pb + ((size_t)(qb0 + qi) * 128 + mb0 + mi) * 256 + ((d & 511) >> 1));
      } else {                                           // V-half rows (o-local)
        int dv = d - 8192;
        int row = dv >> 7;
        stg[k] = *(const short8*)(Vb + (size_t)row * 2048 + m0 + ((dv & 127) >> 1));
      }
    }
  };
  auto WRITES = [&](unsigned char* buf){
    #pragma unroll
    for (int k = 0; k < 6; k++){
      int d = k * 4096 + tid * 16;
      if (k < 2){
        int ti = d >> 9;
        int qi = ti >> 2, mi = ti & 3;
        int lane0 = (d & 511) >> 3;                      // even; chunk = lanes lane0, lane0+1
        #pragma unroll
        for (int idx = 0; idx < 8; idx++){
          int Lp = lane0 + (idx >> 2), r = idx & 3;
          int row = qi * 16 + ((Lp >> 4) << 2) + r;
          int col = mi * 16 + (Lp & 15);
          *(unsigned short*)(buf + ((row * 128 + col * 2) ^ ((row & 7) << 4))) =
              ((const unsigned short*)&stg[k])[idx];
        }
      } else {
        int dv = d - 8192;
        int row = dv >> 7;
        *(short8*)(buf + 8192 + (dv ^ ((row & 7) << 4))) = stg[k];
      }
    }
  };

  // prologue: stage m0=0 into buf[0]
  LOADS(0);
  WRITES(smem[0]);
  __syncthreads();

  for (int t = 0; t < 32; ++t){
    unsigned char* cur = smem[t & 1];
    if (t < 31) LOADS((t + 1) * 64);                     // latency hides under PV
    short8 af[4][2], bf[2][2];
    #pragma unroll
    for (int ni = 0; ni < 4; ni++)
      #pragma unroll
      for (int kc = 0; kc < 2; kc++){
        int row = ni * 16 + l15;
        af[ni][kc] = *(const short8*)(cur + ((row * 128 + kc * 64 + g * 16) ^ ((row & 7) << 4)));
      }
    #pragma unroll
    for (int oi = 0; oi < 2; oi++)
      #pragma unroll
      for (int kc = 0; kc < 2; kc++){
        int row = w * 32 + oi * 16 + l15;
        bf[oi][kc] = *(const short8*)(cur + 8192 + ((row * 128 + kc * 64 + g * 16) ^ ((row & 7) << 4)));
      }
    #pragma unroll
    for (int ni = 0; ni < 4; ni++)
      #pragma unroll
      for (int oi = 0; oi < 2; oi++)
        #pragma unroll
        for (int kc = 0; kc < 2; kc++)
          acc[ni][oi] = __builtin_amdgcn_mfma_f32_16x16x32_bf16(af[ni][kc], bf[oi][kc], acc[ni][oi], 0, 0, 0);
    if (t < 31){
      WRITES(smem[(t + 1) & 1]);
      __syncthreads();                                   // next buf ready; cur reads done
    }
  }
  float inv[4][4];
  #pragma unroll
  for (int ni = 0; ni < 4; ni++)
    #pragma unroll
    for (int r = 0; r < 4; r++)
      inv[ni][r] = 1.0f / sbuf[(size_t)b * 2048 + n0 + ni * 16 + g * 4 + r];
  #pragma unroll
  for (int oi = 0; oi < 2; oi++){
    float cm = -1e30f;
    #pragma unroll
    for (int ni = 0; ni < 4; ni++)
      #pragma unroll
      for (int r = 0; r < 4; r++)
        cm = fmaxf(cm, acc[ni][oi][r] * inv[ni][r]);
    cm = fmaxf(cm, __shfl_xor(cm, 16));
    cm = fmaxf(cm, __shfl_xor(cm, 32));
    if (lane < 16)
      atomicMax(&tmaxe[b * 256 + oh * 128 + w * 32 + oi * 16 + lane], fenc(cm));
  }
}

// ---------------- K5: W_eff = P0 + P1*t + P2 (bf16); bias_eff; w0/w1 -> bf16 -----
__global__ __launch_bounds__(256) void k5_weff(const float* __restrict__ proj_w,
    const float* __restrict__ proj_b, const unsigned* __restrict__ tmaxe,
    const float* __restrict__ params, unsigned short* __restrict__ weff,
    float* __restrict__ beff, unsigned short* __restrict__ w0b,
    unsigned short* __restrict__ w1b){
  const int b = blockIdx.y, o = blockIdx.x;
  const int c = threadIdx.x;                  // 256
  float t = fdec(tmaxe[b * 256 + c]);
  float p0 = proj_w[o * 768 + c];
  float p1 = proj_w[o * 768 + 256 + c];
  float p2 = proj_w[o * 768 + 512 + c];
  weff[((size_t)b * 64 + o) * 256 + c] = f2bf(p0 + p1 * t + p2);
  float s = p0 * t;
  #pragma unroll
  for (int d = 1; d < 64; d <<= 1) s += __shfl_xor(s, d);
  __shared__ float sm[4];
  if ((c & 63) == 0) sm[c >> 6] = s;
  __syncthreads();
  if (c == 0) beff[b * 64 + o] = proj_b[o] - (sm[0] + sm[1] + sm[2] + sm[3]);
  if (c < 64)        w0b[((size_t)b * 64 + o) * 64 + c] = f2bf(params[b * 8385 + o * 64 + c]);
  else if (c < 128)  w1b[((size_t)b * 64 + o) * 64 + (c - 64)] = f2bf(params[b * 8385 + 4096 + o * 64 + (c - 64)]);
}

// ---------------- K6: fused scene pipeline (scene read exactly once) -------------
__global__ __launch_bounds__(512) void k6_main(const float* __restrict__ Sg,
    const unsigned short* __restrict__ weff, const float* __restrict__ beff,
    const unsigned short* __restrict__ w0b, const unsigned short* __restrict__ w1b,
    const float* __restrict__ params, float* __restrict__ out){
  const int b = blockIdx.y, nt = blockIdx.x;
  const int n0 = nt * 256;
  const int tid = threadIdx.x, lane = tid & 63, w = tid >> 6;
  const int l15 = lane & 15, g = lane >> 4;
  __shared__ __align__(16) unsigned char smem[65536];
  unsigned short* H0 = (unsigned short*)smem;            // [n][64] XOR-swizzled, 32 KB
  unsigned char*  Ub = smem + 32768;                     // Bs32 (16KB) then H1 (32KB)
  unsigned short* H1 = (unsigned short*)Ub;

  const float* Sb = Sg + (size_t)b * 256 * 16384;
  const unsigned short* We = weff + (size_t)b * 64 * 256;
  f32x4 a0[4][2];
  #pragma unroll
  for (int mi = 0; mi < 4; mi++)
    #pragma unroll
    for (int ni = 0; ni < 2; ni++) a0[mi][ni] = (f32x4){0.f,0.f,0.f,0.f};

  const int scc = tid & 31;                   // c row within k-tile
  const int snb = (tid >> 5) * 16;            // 16 n per thread
  for (int k0 = 0; k0 < 256; k0 += 32){
    const float* src = Sb + (size_t)(k0 + scc) * 16384 + n0 + snb;
    float4 v0 = ((const float4*)src)[0];
    float4 v1 = ((const float4*)src)[1];
    float4 v2 = ((const float4*)src)[2];
    float4 v3 = ((const float4*)src)[3];
    float vals[16] = {v0.x,v0.y,v0.z,v0.w, v1.x,v1.y,v1.z,v1.w,
                      v2.x,v2.y,v2.z,v2.w, v3.x,v3.y,v3.z,v3.w};
    #pragma unroll
    for (int j = 0; j < 16; j++){
      int n = snb + j;
      unsigned byteo = ((unsigned)(n * 64 + scc * 2)) ^ ((unsigned)((n >> 1) & 3) << 4);
      *(unsigned short*)(Ub + byteo) = f2bf(vals[j]);
    }
    __syncthreads();
    short8 bf0[2];
    #pragma unroll
    for (int ni = 0; ni < 2; ni++){
      int n = w * 32 + ni * 16 + l15;
      bf0[ni] = *(const short8*)(Ub + (((unsigned)(n * 64 + g * 16)) ^ ((unsigned)((n >> 1) & 3) << 4)));
    }
    #pragma unroll
    for (int mi = 0; mi < 4; mi++){
      short8 af = *(const short8*)(We + (mi * 16 + l15) * 256 + k0 + g * 8);
      #pragma unroll
      for (int ni = 0; ni < 2; ni++)
        a0[mi][ni] = __builtin_amdgcn_mfma_f32_16x16x32_bf16(af, bf0[ni], a0[mi][ni], 0, 0, 0);
    }
    __syncthreads();
  }
  const float* be = beff + b * 64;
  #pragma unroll
  for (int mi = 0; mi < 4; mi++)
    #pragma unroll
    for (int ni = 0; ni < 2; ni++){
      int n = w * 32 + ni * 16 + l15;
      unsigned base = ((unsigned)(n * 128 + mi * 32 + g * 8)) ^ ((unsigned)((n & 7) << 4));
      unsigned short hh[4];
      #pragma unroll
      for (int r = 0; r < 4; r++){
        int o = mi * 16 + g * 4 + r;
        hh[r] = f2bf(fmaxf(a0[mi][ni][r] + be[o], 0.f));
      }
      *(unsigned*)((unsigned char*)H0 + base)     = (unsigned)hh[0] | ((unsigned)hh[1] << 16);
      *(unsigned*)((unsigned char*)H0 + base + 4) = (unsigned)hh[2] | ((unsigned)hh[3] << 16);
    }
  __syncthreads();
  f32x4 a1[4][2];
  #pragma unroll
  for (int mi = 0; mi < 4; mi++)
    #pragma unroll
    for (int ni = 0; ni < 2; ni++) a1[mi][ni] = (f32x4){0.f,0.f,0.f,0.f};
  const unsigned short* W0 = w0b + (size_t)b * 4096;
  #pragma unroll
  for (int ks = 0; ks < 2; ks++){
    short8 bfh[2];
    #pragma unroll
    for (int ni = 0; ni < 2; ni++){
      int n = w * 32 + ni * 16 + l15;
      unsigned off = ((unsigned)(n * 128 + ks * 64 + g * 16)) ^ ((unsigned)((n & 7) << 4));
      bfh[ni] = *(const short8*)((unsigned char*)H0 + off);
    }
    #pragma unroll
    for (int mi = 0; mi < 4; mi++){
      short8 af = *(const short8*)(W0 + (mi * 16 + l15) * 64 + ks * 32 + g * 8);
      #pragma unroll
      for (int ni = 0; ni < 2; ni++)
        a1[mi][ni] = __builtin_amdgcn_mfma_f32_16x16x32_bf16(af, bfh[ni], a1[mi][ni], 0, 0, 0);
    }
  }
  const float* pp = params + (size_t)b * 8385;
  const float* b0p = pp + 8256;
  #pragma unroll
  for (int mi = 0; mi < 4; mi++)
    #pragma unroll
    for (int ni = 0; ni < 2; ni++){
      int n = w * 32 + ni * 16 + l15;
      unsigned base = ((unsigned)(n * 128 + mi * 32 + g * 8)) ^ ((unsigned)((n & 7) << 4));
      unsigned short hh[4];
      #pragma unroll
      for (int r = 0; r < 4; r++){
        int o = mi * 16 + g * 4 + r;
        hh[r] = f2bf(fmaxf(a1[mi][ni][r] + b0p[o], 0.f));
      }
      *(unsigned*)((unsigned char*)H1 + base)     = (unsigned)hh[0] | ((unsigned)hh[1] << 16);
      *(unsigned*)((unsigned char*)H1 + base + 4) = (unsigned)hh[2] | ((unsigned)hh[3] << 16);
    }
  __syncthreads();
  f32x4 a2[4][2];
  #pragma unroll
  for (int mi = 0; mi < 4; mi++)
    #pragma unroll
    for (int ni = 0; ni < 2; ni++) a2[mi][ni] = (f32x4){0.f,0.f,0.f,0.f};
  const unsigned short* W1 = w1b + (size_t)b * 4096;
  #pragma unroll
  for (int ks = 0; ks < 2; ks++){
    short8 bfh[2];
    #pragma unroll
    for (int ni = 0; ni < 2; ni++){
      int n = w * 32 + ni * 16 + l15;
      unsigned off = ((unsigned)(n * 128 + ks * 64 + g * 16)) ^ ((unsigned)((n & 7) << 4));
      bfh[ni] = *(const short8*)((unsigned char*)H1 + off);
    }
    #pragma unroll
    for (int mi = 0; mi < 4; mi++){
      short8 af = *(const short8*)(W1 + (mi * 16 + l15) * 64 + ks * 32 + g * 8);
      #pragma unroll
      for (int ni = 0; ni < 2; ni++)
        a2[mi][ni] = __builtin_amdgcn_mfma_f32_16x16x32_bf16(af, bfh[ni], a2[mi][ni], 0, 0, 0);
    }
  }
  const float* b1p = pp + 8320;
  const float* w2p = pp + 8192;
  float b2v = pp[8384];
  #pragma unroll
  for (int ni = 0; ni < 2; ni++){
    float t = 0.f;
    #pragma unroll
    for (int mi = 0; mi < 4; mi++)
      #pragma unroll
      for (int r = 0; r < 4; r++){
        int o = mi * 16 + g * 4 + r;
        t += w2p[o] * fmaxf(a2[mi][ni][r] + b1p[o], 0.f);
      }
    t += __shfl_xor(t, 16);
    t += __shfl_xor(t, 32);
    if (lane < 16)
      out[(size_t)b * 16384 + n0 + w * 32 + ni * 16 + l15] = t + b2v;
  }
}

extern "C" void kernel_launch(void* const* d_in, const int* in_sizes, int n_in,
                              void* d_out, int out_size, void* d_ws, size_t ws_size,
                              hipStream_t stream){
  const float* scene = (const float*)d_in[0];
  const float* tmpl  = (const float*)d_in[1];
  const float* qw    = (const float*)d_in[2];
  const float* kw    = (const float*)d_in[3];
  const float* vw    = (const float*)d_in[4];
  const float* pw    = (const float*)d_in[5];
  const float* pb    = (const float*)d_in[6];
  const float* cw    = (const float*)d_in[7];
  const float* cb    = (const float*)d_in[8];
  float* out = (float*)d_out;
  char* ws = (char*)d_ws;

  unsigned short* Q      = (unsigned short*)(ws + 0);                    // 2 MB
  unsigned short* K      = (unsigned short*)(ws + (2u << 20));           // 2 MB
  unsigned short* V      = (unsigned short*)(ws + (4u << 20));           // 8 MB
  unsigned*       pooledEnc = (unsigned*)(ws + (12u << 20));             // 8 KB
  unsigned*       tmaxe  = (unsigned*)(ws + (12u << 20) + 8192);         // 8 KB
  float*          params = (float*)(ws + (12u << 20) + 16384);           // 268 KB
  unsigned short* w0b    = (unsigned short*)(ws + (13u << 20));          // 64 KB
  unsigned short* w1b    = (unsigned short*)(ws + (13u << 20) + 65536);  // 64 KB
  unsigned short* weff   = (unsigned short*)(ws + (13u << 20) + 131072); // 256 KB
  float*          beff   = (float*)(ws + (13u << 20) + 131072 + 262144); // 2 KB
  float*          sbuf   = (float*)(ws + (14u << 20));                   // 64 KB
  unsigned short* Wbf    = (unsigned short*)(ws + (14u << 20) + 131072); // 192 KB
  unsigned short* Pbuf   = (unsigned short*)(ws + (16u << 20));          // up to 67 MB
  unsigned short* Tt     = Pbuf;   // 8 MB; dead before kA writes Pbuf (stream order)

  const size_t pPerBatch = (size_t)2048 * 2048 * 2;
  size_t avail = ws_size > (16u << 20) ? ws_size - (16u << 20) : 0;
  int nb = 8, bshift = 3;
  while (nb > 1 && (size_t)nb * pPerBatch > avail){ nb >>= 1; bshift--; }

  k0w<<<dim3(96), dim3(256), 0, stream>>>(qw, kw, vw, Wbf, tmaxe, pooledEnc);
  k0_tt<<<dim3(8, 16, 8), dim3(256), 0, stream>>>(tmpl, Tt, pooledEnc);
  k23_qkv_params<<<dim3(512 + 2097), dim3(256), 0, stream>>>(Wbf, Tt, Q, K, V,
                                                             pooledEnc, cw, cb, params);
  for (int b0 = 0; b0 < 8; b0 += nb){
    kA_scores<<<dim3(64 * nb), dim3(512), 0, stream>>>(Q, K, Pbuf, sbuf, b0, bshift);
    kB_pv<<<dim3(64 * nb), dim3(256), 0, stream>>>(Pbuf, V, sbuf, tmaxe, b0, bshift);
  }
  k5_weff<<<dim3(64, 8), dim3(256), 0, stream>>>(pw, pb, tmaxe, params, weff, beff, w0b, w1b);
  k6_main<<<dim3(64, 8), dim3(512), 0, stream>>>(scene, weff, beff, w0b, w1b, params, out);
}

// Round 12
// 144.569 us; speedup vs baseline: 1.2161x; 1.0482x over previous
//
#include <hip/hip_runtime.h>

// DynamicConvolution fused pipeline for MI355X (gfx950).
// R12 (base = R11, 151.5): kA computes SWAPPED QK (mfma(K,Q) -> D[m][q]) so
// each lane stores 4 consecutive m of one q -> P written row-major [q][2048]
// directly. kB's P staging becomes identical to its proven V path (16B read +
// one swizzled b128 LDS write), deleting 16 scalar ds_write_u16/thread/chunk.
// kB at 3 WG/CU (launch_bounds(256,3)). k6 prefetches next scene k-tile.
// Stages: k0w -> k0_tt -> k23 qkv+params -> kA exp(QK^T) -> kB PV+tmax ->
//         k5 W_eff -> k6 fused scene MLP.

typedef __attribute__((ext_vector_type(8))) short short8;
typedef __attribute__((ext_vector_type(4))) short short4v;
typedef __attribute__((ext_vector_type(4))) float f32x4;

__device__ __forceinline__ unsigned short f2bf(float f){
  unsigned u = __float_as_uint(f);
  u += 0x7FFFu + ((u >> 16) & 1u);           // round-to-nearest-even
  return (unsigned short)(u >> 16);
}
// monotone float<->uint for atomicMax on floats (incl. negatives)
__device__ __forceinline__ unsigned fenc(float f){
  unsigned u = __float_as_uint(f);
  return (u & 0x80000000u) ? ~u : (u | 0x80000000u);
}
__device__ __forceinline__ float fdec(unsigned k){
  unsigned u = (k & 0x80000000u) ? (k & 0x7FFFFFFFu) : ~k;
  return __uint_as_float(u);
}

// ---------------- k0w: Wbf[384][256] bf16 (q*0.125 folded); init tmaxe/pooledEnc -
__global__ __launch_bounds__(256) void k0w(const float* __restrict__ qw,
    const float* __restrict__ kw, const float* __restrict__ vw,
    unsigned short* __restrict__ Wbf, unsigned* __restrict__ tmaxe,
    unsigned* __restrict__ pooledEnc){
  if (blockIdx.x == 0){
    const unsigned ninf = fenc(-3.0e38f);
    for (int i = threadIdx.x; i < 2048; i += 256){
      tmaxe[i] = 0u;                          // floor for encoded O-max
      pooledEnc[i] = ninf;                    // true -inf floor for pooled max
    }
  }
  const int e = (blockIdx.x * 256 + threadIdx.x) * 4;   // 96 WGs * 1024 = 98304
  const int row = e >> 8, c = e & 255;
  const float* src;
  float scl = 1.0f;
  if (row < 64){ src = qw + row * 256 + c; scl = 0.125f; }
  else if (row < 128){ src = kw + (row - 64) * 256 + c; }
  else { src = vw + (row - 128) * 256 + c; }
  float4 v = *(const float4*)src;
  short4v o;
  o[0] = (short)f2bf(v.x * scl); o[1] = (short)f2bf(v.y * scl);
  o[2] = (short)f2bf(v.z * scl); o[3] = (short)f2bf(v.w * scl);
  *(short4v*)(Wbf + e) = o;
}

// ---------------- k0_tt: Tt[b][n][c] = bf16(T[b][c][n]); pooled max fold ---------
__global__ __launch_bounds__(256) void k0_tt(const float* __restrict__ T,
    unsigned short* __restrict__ Tt, unsigned* __restrict__ pooledEnc){
  const int b = blockIdx.x, nt = blockIdx.y, ct = blockIdx.z;
  const int n0 = nt * 128, c0 = ct * 32;
  const int tid = threadIdx.x;
  __shared__ float Ls[32][129];
  const int cr = tid >> 3, nq = tid & 7;      // 32 c-rows x 8 n-chunks(16 f32)
  const float* src = T + ((size_t)b * 256 + c0 + cr) * 2048 + n0 + nq * 16;
  float4 v0 = ((const float4*)src)[0];
  float4 v1 = ((const float4*)src)[1];
  float4 v2 = ((const float4*)src)[2];
  float4 v3 = ((const float4*)src)[3];
  float mx = fmaxf(fmaxf(fmaxf(v0.x, v0.y), fmaxf(v0.z, v0.w)),
                   fmaxf(fmaxf(v1.x, v1.y), fmaxf(v1.z, v1.w)));
  mx = fmaxf(mx, fmaxf(fmaxf(fmaxf(v2.x, v2.y), fmaxf(v2.z, v2.w)),
                       fmaxf(fmaxf(v3.x, v3.y), fmaxf(v3.z, v3.w))));
  mx = fmaxf(mx, __shfl_xor(mx, 1));
  mx = fmaxf(mx, __shfl_xor(mx, 2));
  mx = fmaxf(mx, __shfl_xor(mx, 4));
  if (nq == 0) atomicMax(&pooledEnc[b * 256 + c0 + cr], fenc(mx));
  float* lr = &Ls[cr][nq * 16];
  *(float4*)lr = v0; *(float4*)(lr + 4) = v1;
  *(float4*)(lr + 8) = v2; *(float4*)(lr + 12) = v3;
  __syncthreads();
  const int nr = tid >> 1, ch = tid & 1;      // 128 n-rows x 2 c-halves(16)
  unsigned short ob[16];
  #pragma unroll
  for (int j = 0; j < 16; j++) ob[j] = f2bf(Ls[ch * 16 + j][nr]);
  unsigned short* dst = Tt + ((size_t)b * 2048 + n0 + nr) * 256 + c0 + ch * 16;
  *(short8*)dst = *(short8*)&ob[0];
  *(short8*)(dst + 8) = *(short8*)&ob[8];
}

// ---------------- k23: fused k2 (QKV gemm, wg<512) + k3 (params gemv) ------------
__global__ __launch_bounds__(256) void k23_qkv_params(
    const unsigned short* __restrict__ Wbf, const unsigned short* __restrict__ Tt,
    unsigned short* __restrict__ qo, unsigned short* __restrict__ ko,
    unsigned short* __restrict__ vt,
    const unsigned* __restrict__ pooledEnc, const float* __restrict__ cw,
    const float* __restrict__ cb, float* __restrict__ params){
  const int wg = blockIdx.x;
  const int tid = threadIdx.x, lane = tid & 63, w = tid >> 6;
  if (wg >= 512){
    // ---- k3 body: params[b][r] = pooled[b].cw[r] + cb[r]
    __shared__ float P[8 * 256];
    for (int i = tid; i < 2048; i += 256) P[i] = fdec(pooledEnc[i]);
    __syncthreads();
    const int r = (wg - 512) * 4 + w;
    if (r >= 8385) return;
    float4 c4 = ((const float4*)(cw + (size_t)r * 256))[lane];
    float bias = cb[r];
    #pragma unroll
    for (int b = 0; b < 8; b++){
      const float* pbp = P + b * 256 + lane * 4;
      float s = c4.x * pbp[0] + c4.y * pbp[1] + c4.z * pbp[2] + c4.w * pbp[3];
      #pragma unroll
      for (int d = 1; d < 64; d <<= 1) s += __shfl_xor(s, d);
      if (lane == 0) params[b * 8385 + r] = s + bias;
    }
    return;
  }
  // ---- k2 body (R5-proven): no LDS, direct global frags
  const int b = wg & 7, nt = wg >> 3;
  const int n0 = nt * 32;
  const int l15 = lane & 15, g = lane >> 4;
  const unsigned short* Tb = Tt + (size_t)b * 2048 * 256;

  f32x4 aqk[2][2], av[4][2];
  #pragma unroll
  for (int i = 0; i < 2; i++)
    #pragma unroll
    for (int nf = 0; nf < 2; nf++) aqk[i][nf] = (f32x4){0.f,0.f,0.f,0.f};
  #pragma unroll
  for (int j = 0; j < 4; j++)
    #pragma unroll
    for (int nf = 0; nf < 2; nf++) av[j][nf] = (f32x4){0.f,0.f,0.f,0.f};

  #pragma unroll 2
  for (int kc = 0; kc < 8; kc++){
    short8 bfr[2];
    #pragma unroll
    for (int nf = 0; nf < 2; nf++)
      bfr[nf] = *(const short8*)(Tb + (size_t)(n0 + nf * 16 + l15) * 256 + kc * 32 + g * 8);
    short8 aq[2];
    #pragma unroll
    for (int i = 0; i < 2; i++)
      aq[i] = *(const short8*)(Wbf + (size_t)((2 * w + i) * 16 + l15) * 256 + kc * 32 + g * 8);
    short8 afv[4];
    #pragma unroll
    for (int j = 0; j < 4; j++)
      afv[j] = *(const short8*)(Wbf + (size_t)(128 + (4 * w + j) * 16 + l15) * 256 + kc * 32 + g * 8);
    #pragma unroll
    for (int i = 0; i < 2; i++)
      #pragma unroll
      for (int nf = 0; nf < 2; nf++)
        aqk[i][nf] = __builtin_amdgcn_mfma_f32_16x16x32_bf16(aq[i], bfr[nf], aqk[i][nf], 0, 0, 0);
    #pragma unroll
    for (int j = 0; j < 4; j++)
      #pragma unroll
      for (int nf = 0; nf < 2; nf++)
        av[j][nf] = __builtin_amdgcn_mfma_f32_16x16x32_bf16(bfr[nf], afv[j], av[j][nf], 0, 0, 0);
  }
  unsigned short* qk = (w < 2) ? qo : ko;
  #pragma unroll
  for (int i = 0; i < 2; i++)
    #pragma unroll
    for (int nf = 0; nf < 2; nf++){
      int n = n0 + nf * 16 + l15;
      int cbase = (w & 1) * 32 + i * 16 + g * 4;
      short4v pk;
      #pragma unroll
      for (int r = 0; r < 4; r++) pk[r] = (short)f2bf(aqk[i][nf][r]);
      *(short4v*)(qk + ((size_t)b * 2048 + n) * 64 + cbase) = pk;
    }
  #pragma unroll
  for (int j = 0; j < 4; j++)
    #pragma unroll
    for (int nf = 0; nf < 2; nf++){
      int o = (4 * w + j) * 16 + l15;
      int nb2 = n0 + nf * 16 + g * 4;
      short4v pv;
      #pragma unroll
      for (int r = 0; r < 4; r++) pv[r] = (short)f2bf(av[j][nf][r]);
      *(short4v*)(vt + ((size_t)b * 256 + o) * 2048 + nb2) = pv;
    }
}

// ---------------- kA v4: swapped QK -> P row-major [q][2048] directly ------------
// grid 64*nb x 512 thr (b = wg&bmask XCD-local, qt -> 32 q-rows). Wave w owns
// m-chunk [w*256,+256). mfma(K,Q) -> D[m][q]: lane (g,l15) holds 4 consecutive
// m (= mi*16+g*4+r) for q = qi*16+l15 -> one short4v row-major store per tile.
__global__ __launch_bounds__(512, 4) void kA_scores(
    const unsigned short* __restrict__ Qg, const unsigned short* __restrict__ Kg,
    unsigned short* __restrict__ Pg, float* __restrict__ sbuf,
    int b0, int bshift){
  const int wg = blockIdx.x;
  const int bmask = (1 << bshift) - 1;
  const int b = b0 + (wg & bmask);
  const int q0 = (wg >> bshift) * 32;
  const int tid = threadIdx.x, lane = tid & 63, w = tid >> 6;
  const int l15 = lane & 15, g = lane >> 4;
  __shared__ float wsum[32][8];
  const unsigned short* Qb = Qg + (size_t)b * 2048 * 64;
  const unsigned short* Kb = Kg + (size_t)b * 2048 * 64;
  unsigned short* Pb = Pg + (size_t)(wg & bmask) * 2048 * 2048;

  short8 qf[2][2];
  #pragma unroll
  for (int qi = 0; qi < 2; qi++)
    #pragma unroll
    for (int kc = 0; kc < 2; kc++)
      qf[qi][kc] = *(const short8*)(Qb + (size_t)(q0 + qi * 16 + l15) * 64 + kc * 32 + g * 8);

  float ps[2] = {0.f, 0.f};                   // per-lane partial for q = qi*16+l15

  const int wm0 = w * 256;
  #pragma unroll
  for (int mt = 0; mt < 4; ++mt){
    const int mb = wm0 + mt * 64;
    short8 kf[4][2];
    #pragma unroll
    for (int mi = 0; mi < 4; mi++)
      #pragma unroll
      for (int kc = 0; kc < 2; kc++)
        kf[mi][kc] = *(const short8*)(Kb + (size_t)(mb + mi * 16 + l15) * 64 + kc * 32 + g * 8);
    #pragma unroll
    for (int qi = 0; qi < 2; qi++){
      f32x4 sa[4];
      #pragma unroll
      for (int mi = 0; mi < 4; mi++) sa[mi] = (f32x4){0.f,0.f,0.f,0.f};
      #pragma unroll
      for (int mi = 0; mi < 4; mi++)
        #pragma unroll
        for (int kc = 0; kc < 2; kc++)
          sa[mi] = __builtin_amdgcn_mfma_f32_16x16x32_bf16(kf[mi][kc], qf[qi][kc], sa[mi], 0, 0, 0);
      #pragma unroll
      for (int mi = 0; mi < 4; mi++){
        short4v pk;
        #pragma unroll
        for (int r = 0; r < 4; r++){
          float p = __expf(sa[mi][r]);        // sa[mi][r] = S[m=mb+mi*16+g*4+r][q]
          ps[qi] += p;
          pk[r] = (short)f2bf(p);
        }
        *(short4v*)(Pb + (size_t)(q0 + qi * 16 + l15) * 2048 + mb + mi * 16 + g * 4) = pk;
      }
    }
  }
  #pragma unroll
  for (int qi = 0; qi < 2; qi++){
    float t = ps[qi];
    t += __shfl_xor(t, 16);
    t += __shfl_xor(t, 32);                   // sum over the 4 g-groups
    if (lane < 16) wsum[qi * 16 + l15][w] = t;
  }
  __syncthreads();
  if (tid < 32){
    float t = 0.f;
    #pragma unroll
    for (int i = 0; i < 8; i++) t += wsum[tid][i];
    sbuf[(size_t)b * 2048 + q0 + tid] = t;
  }
}

// ---------------- kB v4: O = P@V^T; P staging now identical to V path ------------
// grid 64*nb (b; oh = o-half; nt -> 64 n-rows). LDS dbuf 2x24KB (P 8KB row-major
// swizzled + V-half 16KB). All staging: contiguous 16B read -> one swizzled
// b128 LDS write. 3 WG/CU.
__global__ __launch_bounds__(256, 3) void kB_pv(
    const unsigned short* __restrict__ Pg, const unsigned short* __restrict__ Vt,
    const float* __restrict__ sbuf, unsigned* __restrict__ tmaxe,
    int b0, int bshift){
  const int wg = blockIdx.x;
  const int bmask = (1 << bshift) - 1;
  const int b = b0 + (wg & bmask);
  const int rest = wg >> bshift;
  const int oh = rest & 1;
  const int n0 = (rest >> 1) * 64;
  const int tid = threadIdx.x, lane = tid & 63, w = tid >> 6;
  const int l15 = lane & 15, g = lane >> 4;
  __shared__ __align__(16) unsigned char smem[2][24576];  // dbuf: Pl 8KB | Vl 16KB

  const unsigned short* Pb = Pg + (size_t)(wg & bmask) * 2048 * 2048;
  const unsigned short* Vb = Vt + ((size_t)b * 256 + oh * 128) * 2048;

  f32x4 acc[4][2];
  #pragma unroll
  for (int ni = 0; ni < 4; ni++)
    #pragma unroll
    for (int oi = 0; oi < 2; oi++) acc[ni][oi] = (f32x4){0.f,0.f,0.f,0.f};

  short8 stg[6];
  auto LOADS = [&](int m0){
    #pragma unroll
    for (int k = 0; k < 6; k++){
      int d = k * 4096 + tid * 16;
      if (k < 2){                                        // P rows (n-local, row-major)
        int row = d >> 7;
        stg[k] = *(const short8*)(Pb + (size_t)(n0 + row) * 2048 + m0 + ((d & 127) >> 1));
      } else {                                           // V-half rows (o-local)
        int dv = d - 8192;
        int row = dv >> 7;
        stg[k] = *(const short8*)(Vb + (size_t)row * 2048 + m0 + ((dv & 127) >> 1));
      }
    }
  };
  auto WRITES = [&](unsigned char* buf){
    #pragma unroll
    for (int k = 0; k < 6; k++){
      int d = k * 4096 + tid * 16;
      if (k < 2){
        int row = d >> 7;
        *(short8*)(buf + (d ^ ((row & 7) << 4))) = stg[k];
      } else {
        int dv = d - 8192;
        int row = dv >> 7;
        *(short8*)(buf + 8192 + (dv ^ ((row & 7) << 4))) = stg[k];
      }
    }
  };

  LOADS(0);
  WRITES(smem[0]);
  __syncthreads();

  for (int t = 0; t < 32; ++t){
    unsigned char* cur = smem[t & 1];
    if (t < 31) LOADS((t + 1) * 64);                     // latency hides under PV
    short8 af[4][2], bf[2][2];
    #pragma unroll
    for (int ni = 0; ni < 4; ni++)
      #pragma unroll
      for (int kc = 0; kc < 2; kc++){
        int row = ni * 16 + l15;
        af[ni][kc] = *(const short8*)(cur + ((row * 128 + kc * 64 + g * 16) ^ ((row & 7) << 4)));
      }
    #pragma unroll
    for (int oi = 0; oi < 2; oi++)
      #pragma unroll
      for (int kc = 0; kc < 2; kc++){
        int row = w * 32 + oi * 16 + l15;
        bf[oi][kc] = *(const short8*)(cur + 8192 + ((row * 128 + kc * 64 + g * 16) ^ ((row & 7) << 4)));
      }
    #pragma unroll
    for (int ni = 0; ni < 4; ni++)
      #pragma unroll
      for (int oi = 0; oi < 2; oi++)
        #pragma unroll
        for (int kc = 0; kc < 2; kc++)
          acc[ni][oi] = __builtin_amdgcn_mfma_f32_16x16x32_bf16(af[ni][kc], bf[oi][kc], acc[ni][oi], 0, 0, 0);
    if (t < 31){
      WRITES(smem[(t + 1) & 1]);
      __syncthreads();                                   // next buf ready; cur reads done
    }
  }
  float inv[4][4];
  #pragma unroll
  for (int ni = 0; ni < 4; ni++)
    #pragma unroll
    for (int r = 0; r < 4; r++)
      inv[ni][r] = 1.0f / sbuf[(size_t)b * 2048 + n0 + ni * 16 + g * 4 + r];
  #pragma unroll
  for (int oi = 0; oi < 2; oi++){
    float cm = -1e30f;
    #pragma unroll
    for (int ni = 0; ni < 4; ni++)
      #pragma unroll
      for (int r = 0; r < 4; r++)
        cm = fmaxf(cm, acc[ni][oi][r] * inv[ni][r]);
    cm = fmaxf(cm, __shfl_xor(cm, 16));
    cm = fmaxf(cm, __shfl_xor(cm, 32));
    if (lane < 16)
      atomicMax(&tmaxe[b * 256 + oh * 128 + w * 32 + oi * 16 + lane], fenc(cm));
  }
}

// ---------------- K5: W_eff = P0 + P1*t + P2 (bf16); bias_eff; w0/w1 -> bf16 -----
__global__ __launch_bounds__(256) void k5_weff(const float* __restrict__ proj_w,
    const float* __restrict__ proj_b, const unsigned* __restrict__ tmaxe,
    const float* __restrict__ params, unsigned short* __restrict__ weff,
    float* __restrict__ beff, unsigned short* __restrict__ w0b,
    unsigned short* __restrict__ w1b){
  const int b = blockIdx.y, o = blockIdx.x;
  const int c = threadIdx.x;                  // 256
  float t = fdec(tmaxe[b * 256 + c]);
  float p0 = proj_w[o * 768 + c];
  float p1 = proj_w[o * 768 + 256 + c];
  float p2 = proj_w[o * 768 + 512 + c];
  weff[((size_t)b * 64 + o) * 256 + c] = f2bf(p0 + p1 * t + p2);
  float s = p0 * t;
  #pragma unroll
  for (int d = 1; d < 64; d <<= 1) s += __shfl_xor(s, d);
  __shared__ float sm[4];
  if ((c & 63) == 0) sm[c >> 6] = s;
  __syncthreads();
  if (c == 0) beff[b * 64 + o] = proj_b[o] - (sm[0] + sm[1] + sm[2] + sm[3]);
  if (c < 64)        w0b[((size_t)b * 64 + o) * 64 + c] = f2bf(params[b * 8385 + o * 64 + c]);
  else if (c < 128)  w1b[((size_t)b * 64 + o) * 64 + (c - 64)] = f2bf(params[b * 8385 + 4096 + o * 64 + (c - 64)]);
}

// ---------------- K6: fused scene pipeline (scene read exactly once) -------------
// R12: register prefetch of next scene k-tile (loads in flight across barrier).
__global__ __launch_bounds__(512) void k6_main(const float* __restrict__ Sg,
    const unsigned short* __restrict__ weff, const float* __restrict__ beff,
    const unsigned short* __restrict__ w0b, const unsigned short* __restrict__ w1b,
    const float* __restrict__ params, float* __restrict__ out){
  const int b = blockIdx.y, nt = blockIdx.x;
  const int n0 = nt * 256;
  const int tid = threadIdx.x, lane = tid & 63, w = tid >> 6;
  const int l15 = lane & 15, g = lane >> 4;
  __shared__ __align__(16) unsigned char smem[65536];
  unsigned short* H0 = (unsigned short*)smem;            // [n][64] XOR-swizzled, 32 KB
  unsigned char*  Ub = smem + 32768;                     // Bs32 (16KB) then H1 (32KB)
  unsigned short* H1 = (unsigned short*)Ub;

  const float* Sb = Sg + (size_t)b * 256 * 16384;
  const unsigned short* We = weff + (size_t)b * 64 * 256;
  f32x4 a0[4][2];
  #pragma unroll
  for (int mi = 0; mi < 4; mi++)
    #pragma unroll
    for (int ni = 0; ni < 2; ni++) a0[mi][ni] = (f32x4){0.f,0.f,0.f,0.f};

  const int scc = tid & 31;                   // c row within k-tile
  const int snb = (tid >> 5) * 16;            // 16 n per thread
  const float* src0 = Sb + (size_t)scc * 16384 + n0 + snb;
  float4 v0 = ((const float4*)src0)[0];
  float4 v1 = ((const float4*)src0)[1];
  float4 v2 = ((const float4*)src0)[2];
  float4 v3 = ((const float4*)src0)[3];
  for (int k0 = 0; k0 < 256; k0 += 32){
    float vals[16] = {v0.x,v0.y,v0.z,v0.w, v1.x,v1.y,v1.z,v1.w,
                      v2.x,v2.y,v2.z,v2.w, v3.x,v3.y,v3.z,v3.w};
    #pragma unroll
    for (int j = 0; j < 16; j++){
      int n = snb + j;
      unsigned byteo = ((unsigned)(n * 64 + scc * 2)) ^ ((unsigned)((n >> 1) & 3) << 4);
      *(unsigned short*)(Ub + byteo) = f2bf(vals[j]);
    }
    if (k0 < 224){                            // prefetch next k-tile into regs
      const float* nsrc = Sb + (size_t)(k0 + 32 + scc) * 16384 + n0 + snb;
      v0 = ((const float4*)nsrc)[0];
      v1 = ((const float4*)nsrc)[1];
      v2 = ((const float4*)nsrc)[2];
      v3 = ((const float4*)nsrc)[3];
    }
    __syncthreads();
    short8 bf0[2];
    #pragma unroll
    for (int ni = 0; ni < 2; ni++){
      int n = w * 32 + ni * 16 + l15;
      bf0[ni] = *(const short8*)(Ub + (((unsigned)(n * 64 + g * 16)) ^ ((unsigned)((n >> 1) & 3) << 4)));
    }
    #pragma unroll
    for (int mi = 0; mi < 4; mi++){
      short8 af = *(const short8*)(We + (mi * 16 + l15) * 256 + k0 + g * 8);
      #pragma unroll
      for (int ni = 0; ni < 2; ni++)
        a0[mi][ni] = __builtin_amdgcn_mfma_f32_16x16x32_bf16(af, bf0[ni], a0[mi][ni], 0, 0, 0);
    }
    __syncthreads();
  }
  const float* be = beff + b * 64;
  #pragma unroll
  for (int mi = 0; mi < 4; mi++)
    #pragma unroll
    for (int ni = 0; ni < 2; ni++){
      int n = w * 32 + ni * 16 + l15;
      unsigned base = ((unsigned)(n * 128 + mi * 32 + g * 8)) ^ ((unsigned)((n & 7) << 4));
      unsigned short hh[4];
      #pragma unroll
      for (int r = 0; r < 4; r++){
        int o = mi * 16 + g * 4 + r;
        hh[r] = f2bf(fmaxf(a0[mi][ni][r] + be[o], 0.f));
      }
      *(unsigned*)((unsigned char*)H0 + base)     = (unsigned)hh[0] | ((unsigned)hh[1] << 16);
      *(unsigned*)((unsigned char*)H0 + base + 4) = (unsigned)hh[2] | ((unsigned)hh[3] << 16);
    }
  __syncthreads();
  f32x4 a1[4][2];
  #pragma unroll
  for (int mi = 0; mi < 4; mi++)
    #pragma unroll
    for (int ni = 0; ni < 2; ni++) a1[mi][ni] = (f32x4){0.f,0.f,0.f,0.f};
  const unsigned short* W0 = w0b + (size_t)b * 4096;
  #pragma unroll
  for (int ks = 0; ks < 2; ks++){
    short8 bfh[2];
    #pragma unroll
    for (int ni = 0; ni < 2; ni++){
      int n = w * 32 + ni * 16 + l15;
      unsigned off = ((unsigned)(n * 128 + ks * 64 + g * 16)) ^ ((unsigned)((n & 7) << 4));
      bfh[ni] = *(const short8*)((unsigned char*)H0 + off);
    }
    #pragma unroll
    for (int mi = 0; mi < 4; mi++){
      short8 af = *(const short8*)(W0 + (mi * 16 + l15) * 64 + ks * 32 + g * 8);
      #pragma unroll
      for (int ni = 0; ni < 2; ni++)
        a1[mi][ni] = __builtin_amdgcn_mfma_f32_16x16x32_bf16(af, bfh[ni], a1[mi][ni], 0, 0, 0);
    }
  }
  const float* pp = params + (size_t)b * 8385;
  const float* b0p = pp + 8256;
  #pragma unroll
  for (int mi = 0; mi < 4; mi++)
    #pragma unroll
    for (int ni = 0; ni < 2; ni++){
      int n = w * 32 + ni * 16 + l15;
      unsigned base = ((unsigned)(n * 128 + mi * 32 + g * 8)) ^ ((unsigned)((n & 7) << 4));
      unsigned short hh[4];
      #pragma unroll
      for (int r = 0; r < 4; r++){
        int o = mi * 16 + g * 4 + r;
        hh[r] = f2bf(fmaxf(a1[mi][ni][r] + b0p[o], 0.f));
      }
      *(unsigned*)((unsigned char*)H1 + base)     = (unsigned)hh[0] | ((unsigned)hh[1] << 16);
      *(unsigned*)((unsigned char*)H1 + base + 4) = (unsigned)hh[2] | ((unsigned)hh[3] << 16);
    }
  __syncthreads();
  f32x4 a2[4][2];
  #pragma unroll
  for (int mi = 0; mi < 4; mi++)
    #pragma unroll
    for (int ni = 0; ni < 2; ni++) a2[mi][ni] = (f32x4){0.f,0.f,0.f,0.f};
  const unsigned short* W1 = w1b + (size_t)b * 4096;
  #pragma unroll
  for (int ks = 0; ks < 2; ks++){
    short8 bfh[2];
    #pragma unroll
    for (int ni = 0; ni < 2; ni++){
      int n = w * 32 + ni * 16 + l15;
      unsigned off = ((unsigned)(n * 128 + ks * 64 + g * 16)) ^ ((unsigned)((n & 7) << 4));
      bfh[ni] = *(const short8*)((unsigned char*)H1 + off);
    }
    #pragma unroll
    for (int mi = 0; mi < 4; mi++){
      short8 af = *(const short8*)(W1 + (mi * 16 + l15) * 64 + ks * 32 + g * 8);
      #pragma unroll
      for (int ni = 0; ni < 2; ni++)
        a2[mi][ni] = __builtin_amdgcn_mfma_f32_16x16x32_bf16(af, bfh[ni], a2[mi][ni], 0, 0, 0);
    }
  }
  const float* b1p = pp + 8320;
  const float* w2p = pp + 8192;
  float b2v = pp[8384];
  #pragma unroll
  for (int ni = 0; ni < 2; ni++){
    float t = 0.f;
    #pragma unroll
    for (int mi = 0; mi < 4; mi++)
      #pragma unroll
      for (int r = 0; r < 4; r++){
        int o = mi * 16 + g * 4 + r;
        t += w2p[o] * fmaxf(a2[mi][ni][r] + b1p[o], 0.f);
      }
    t += __shfl_xor(t, 16);
    t += __shfl_xor(t, 32);
    if (lane < 16)
      out[(size_t)b * 16384 + n0 + w * 32 + ni * 16 + l15] = t + b2v;
  }
}

extern "C" void kernel_launch(void* const* d_in, const int* in_sizes, int n_in,
                              void* d_out, int out_size, void* d_ws, size_t ws_size,
                              hipStream_t stream){
  const float* scene = (const float*)d_in[0];
  const float* tmpl  = (const float*)d_in[1];
  const float* qw    = (const float*)d_in[2];
  const float* kw    = (const float*)d_in[3];
  const float* vw    = (const float*)d_in[4];
  const float* pw    = (const float*)d_in[5];
  const float* pb    = (const float*)d_in[6];
  const float* cw    = (const float*)d_in[7];
  const float* cb    = (const float*)d_in[8];
  float* out = (float*)d_out;
  char* ws = (char*)d_ws;

  unsigned short* Q      = (unsigned short*)(ws + 0);                    // 2 MB
  unsigned short* K      = (unsigned short*)(ws + (2u << 20));           // 2 MB
  unsigned short* V      = (unsigned short*)(ws + (4u << 20));           // 8 MB
  unsigned*       pooledEnc = (unsigned*)(ws + (12u << 20));             // 8 KB
  unsigned*       tmaxe  = (unsigned*)(ws + (12u << 20) + 8192);         // 8 KB
  float*          params = (float*)(ws + (12u << 20) + 16384);           // 268 KB
  unsigned short* w0b    = (unsigned short*)(ws + (13u << 20));          // 64 KB
  unsigned short* w1b    = (unsigned short*)(ws + (13u << 20) + 65536);  // 64 KB
  unsigned short* weff   = (unsigned short*)(ws + (13u << 20) + 131072); // 256 KB
  float*          beff   = (float*)(ws + (13u << 20) + 131072 + 262144); // 2 KB
  float*          sbuf   = (float*)(ws + (14u << 20));                   // 64 KB
  unsigned short* Wbf    = (unsigned short*)(ws + (14u << 20) + 131072); // 192 KB
  unsigned short* Pbuf   = (unsigned short*)(ws + (16u << 20));          // up to 67 MB
  unsigned short* Tt     = Pbuf;   // 8 MB; dead before kA writes Pbuf (stream order)

  const size_t pPerBatch = (size_t)2048 * 2048 * 2;
  size_t avail = ws_size > (16u << 20) ? ws_size - (16u << 20) : 0;
  int nb = 8, bshift = 3;
  while (nb > 1 && (size_t)nb * pPerBatch > avail){ nb >>= 1; bshift--; }

  k0w<<<dim3(96), dim3(256), 0, stream>>>(qw, kw, vw, Wbf, tmaxe, pooledEnc);
  k0_tt<<<dim3(8, 16, 8), dim3(256), 0, stream>>>(tmpl, Tt, pooledEnc);
  k23_qkv_params<<<dim3(512 + 2097), dim3(256), 0, stream>>>(Wbf, Tt, Q, K, V,
                                                             pooledEnc, cw, cb, params);
  for (int b0 = 0; b0 < 8; b0 += nb){
    kA_scores<<<dim3(64 * nb), dim3(512), 0, stream>>>(Q, K, Pbuf, sbuf, b0, bshift);
    kB_pv<<<dim3(64 * nb), dim3(256), 0, stream>>>(Pbuf, V, sbuf, tmaxe, b0, bshift);
  }
  k5_weff<<<dim3(64, 8), dim3(256), 0, stream>>>(pw, pb, tmaxe, params, weff, beff, w0b, w1b);
  k6_main<<<dim3(64, 8), dim3(512), 0, stream>>>(scene, weff, beff, w0b, w1b, params, out);
}

// Round 13
// 140.392 us; speedup vs baseline: 1.2523x; 1.0297x over previous
//
#include <hip/hip_runtime.h>

// DynamicConvolution fused pipeline for MI355X (gfx950).
// R13 (base = R12, 144.6): kB staging converted to async global_load_lds
// (m97 pattern): wave-uniform LDS dest + lane*16, XOR swizzle moved to the
// pre-swizzled GLOBAL source address (linear dest + inv-swz source + swz read).
// Deletes the 48-VGPR stg round-trip and all ds_write VALU; single barrier
// per chunk drains vmcnt. Frag reads / MFMA / epilogue byte-identical to R12.
// Stages: k0w -> k0_tt -> k23 qkv+params -> kA exp(QK^T) -> kB PV+tmax ->
//         k5 W_eff -> k6 fused scene MLP.

typedef __attribute__((ext_vector_type(8))) short short8;
typedef __attribute__((ext_vector_type(4))) short short4v;
typedef __attribute__((ext_vector_type(4))) float f32x4;

__device__ __forceinline__ unsigned short f2bf(float f){
  unsigned u = __float_as_uint(f);
  u += 0x7FFFu + ((u >> 16) & 1u);           // round-to-nearest-even
  return (unsigned short)(u >> 16);
}
// monotone float<->uint for atomicMax on floats (incl. negatives)
__device__ __forceinline__ unsigned fenc(float f){
  unsigned u = __float_as_uint(f);
  return (u & 0x80000000u) ? ~u : (u | 0x80000000u);
}
__device__ __forceinline__ float fdec(unsigned k){
  unsigned u = (k & 0x80000000u) ? (k & 0x7FFFFFFFu) : ~k;
  return __uint_as_float(u);
}

// ---------------- k0w: Wbf[384][256] bf16 (q*0.125 folded); init tmaxe/pooledEnc -
__global__ __launch_bounds__(256) void k0w(const float* __restrict__ qw,
    const float* __restrict__ kw, const float* __restrict__ vw,
    unsigned short* __restrict__ Wbf, unsigned* __restrict__ tmaxe,
    unsigned* __restrict__ pooledEnc){
  if (blockIdx.x == 0){
    const unsigned ninf = fenc(-3.0e38f);
    for (int i = threadIdx.x; i < 2048; i += 256){
      tmaxe[i] = 0u;                          // floor for encoded O-max
      pooledEnc[i] = ninf;                    // true -inf floor for pooled max
    }
  }
  const int e = (blockIdx.x * 256 + threadIdx.x) * 4;   // 96 WGs * 1024 = 98304
  const int row = e >> 8, c = e & 255;
  const float* src;
  float scl = 1.0f;
  if (row < 64){ src = qw + row * 256 + c; scl = 0.125f; }
  else if (row < 128){ src = kw + (row - 64) * 256 + c; }
  else { src = vw + (row - 128) * 256 + c; }
  float4 v = *(const float4*)src;
  short4v o;
  o[0] = (short)f2bf(v.x * scl); o[1] = (short)f2bf(v.y * scl);
  o[2] = (short)f2bf(v.z * scl); o[3] = (short)f2bf(v.w * scl);
  *(short4v*)(Wbf + e) = o;
}

// ---------------- k0_tt: Tt[b][n][c] = bf16(T[b][c][n]); pooled max fold ---------
__global__ __launch_bounds__(256) void k0_tt(const float* __restrict__ T,
    unsigned short* __restrict__ Tt, unsigned* __restrict__ pooledEnc){
  const int b = blockIdx.x, nt = blockIdx.y, ct = blockIdx.z;
  const int n0 = nt * 128, c0 = ct * 32;
  const int tid = threadIdx.x;
  __shared__ float Ls[32][129];
  const int cr = tid >> 3, nq = tid & 7;      // 32 c-rows x 8 n-chunks(16 f32)
  const float* src = T + ((size_t)b * 256 + c0 + cr) * 2048 + n0 + nq * 16;
  float4 v0 = ((const float4*)src)[0];
  float4 v1 = ((const float4*)src)[1];
  float4 v2 = ((const float4*)src)[2];
  float4 v3 = ((const float4*)src)[3];
  float mx = fmaxf(fmaxf(fmaxf(v0.x, v0.y), fmaxf(v0.z, v0.w)),
                   fmaxf(fmaxf(v1.x, v1.y), fmaxf(v1.z, v1.w)));
  mx = fmaxf(mx, fmaxf(fmaxf(fmaxf(v2.x, v2.y), fmaxf(v2.z, v2.w)),
                       fmaxf(fmaxf(v3.x, v3.y), fmaxf(v3.z, v3.w))));
  mx = fmaxf(mx, __shfl_xor(mx, 1));
  mx = fmaxf(mx, __shfl_xor(mx, 2));
  mx = fmaxf(mx, __shfl_xor(mx, 4));
  if (nq == 0) atomicMax(&pooledEnc[b * 256 + c0 + cr], fenc(mx));
  float* lr = &Ls[cr][nq * 16];
  *(float4*)lr = v0; *(float4*)(lr + 4) = v1;
  *(float4*)(lr + 8) = v2; *(float4*)(lr + 12) = v3;
  __syncthreads();
  const int nr = tid >> 1, ch = tid & 1;      // 128 n-rows x 2 c-halves(16)
  unsigned short ob[16];
  #pragma unroll
  for (int j = 0; j < 16; j++) ob[j] = f2bf(Ls[ch * 16 + j][nr]);
  unsigned short* dst = Tt + ((size_t)b * 2048 + n0 + nr) * 256 + c0 + ch * 16;
  *(short8*)dst = *(short8*)&ob[0];
  *(short8*)(dst + 8) = *(short8*)&ob[8];
}

// ---------------- k23: fused k2 (QKV gemm, wg<512) + k3 (params gemv) ------------
__global__ __launch_bounds__(256) void k23_qkv_params(
    const unsigned short* __restrict__ Wbf, const unsigned short* __restrict__ Tt,
    unsigned short* __restrict__ qo, unsigned short* __restrict__ ko,
    unsigned short* __restrict__ vt,
    const unsigned* __restrict__ pooledEnc, const float* __restrict__ cw,
    const float* __restrict__ cb, float* __restrict__ params){
  const int wg = blockIdx.x;
  const int tid = threadIdx.x, lane = tid & 63, w = tid >> 6;
  if (wg >= 512){
    // ---- k3 body: params[b][r] = pooled[b].cw[r] + cb[r]
    __shared__ float P[8 * 256];
    for (int i = tid; i < 2048; i += 256) P[i] = fdec(pooledEnc[i]);
    __syncthreads();
    const int r = (wg - 512) * 4 + w;
    if (r >= 8385) return;
    float4 c4 = ((const float4*)(cw + (size_t)r * 256))[lane];
    float bias = cb[r];
    #pragma unroll
    for (int b = 0; b < 8; b++){
      const float* pbp = P + b * 256 + lane * 4;
      float s = c4.x * pbp[0] + c4.y * pbp[1] + c4.z * pbp[2] + c4.w * pbp[3];
      #pragma unroll
      for (int d = 1; d < 64; d <<= 1) s += __shfl_xor(s, d);
      if (lane == 0) params[b * 8385 + r] = s + bias;
    }
    return;
  }
  // ---- k2 body (R5-proven): no LDS, direct global frags
  const int b = wg & 7, nt = wg >> 3;
  const int n0 = nt * 32;
  const int l15 = lane & 15, g = lane >> 4;
  const unsigned short* Tb = Tt + (size_t)b * 2048 * 256;

  f32x4 aqk[2][2], av[4][2];
  #pragma unroll
  for (int i = 0; i < 2; i++)
    #pragma unroll
    for (int nf = 0; nf < 2; nf++) aqk[i][nf] = (f32x4){0.f,0.f,0.f,0.f};
  #pragma unroll
  for (int j = 0; j < 4; j++)
    #pragma unroll
    for (int nf = 0; nf < 2; nf++) av[j][nf] = (f32x4){0.f,0.f,0.f,0.f};

  #pragma unroll 2
  for (int kc = 0; kc < 8; kc++){
    short8 bfr[2];
    #pragma unroll
    for (int nf = 0; nf < 2; nf++)
      bfr[nf] = *(const short8*)(Tb + (size_t)(n0 + nf * 16 + l15) * 256 + kc * 32 + g * 8);
    short8 aq[2];
    #pragma unroll
    for (int i = 0; i < 2; i++)
      aq[i] = *(const short8*)(Wbf + (size_t)((2 * w + i) * 16 + l15) * 256 + kc * 32 + g * 8);
    short8 afv[4];
    #pragma unroll
    for (int j = 0; j < 4; j++)
      afv[j] = *(const short8*)(Wbf + (size_t)(128 + (4 * w + j) * 16 + l15) * 256 + kc * 32 + g * 8);
    #pragma unroll
    for (int i = 0; i < 2; i++)
      #pragma unroll
      for (int nf = 0; nf < 2; nf++)
        aqk[i][nf] = __builtin_amdgcn_mfma_f32_16x16x32_bf16(aq[i], bfr[nf], aqk[i][nf], 0, 0, 0);
    #pragma unroll
    for (int j = 0; j < 4; j++)
      #pragma unroll
      for (int nf = 0; nf < 2; nf++)
        av[j][nf] = __builtin_amdgcn_mfma_f32_16x16x32_bf16(bfr[nf], afv[j], av[j][nf], 0, 0, 0);
  }
  unsigned short* qk = (w < 2) ? qo : ko;
  #pragma unroll
  for (int i = 0; i < 2; i++)
    #pragma unroll
    for (int nf = 0; nf < 2; nf++){
      int n = n0 + nf * 16 + l15;
      int cbase = (w & 1) * 32 + i * 16 + g * 4;
      short4v pk;
      #pragma unroll
      for (int r = 0; r < 4; r++) pk[r] = (short)f2bf(aqk[i][nf][r]);
      *(short4v*)(qk + ((size_t)b * 2048 + n) * 64 + cbase) = pk;
    }
  #pragma unroll
  for (int j = 0; j < 4; j++)
    #pragma unroll
    for (int nf = 0; nf < 2; nf++){
      int o = (4 * w + j) * 16 + l15;
      int nb2 = n0 + nf * 16 + g * 4;
      short4v pv;
      #pragma unroll
      for (int r = 0; r < 4; r++) pv[r] = (short)f2bf(av[j][nf][r]);
      *(short4v*)(vt + ((size_t)b * 256 + o) * 2048 + nb2) = pv;
    }
}

// ---------------- kA v4: swapped QK -> P row-major [q][2048] directly ------------
__global__ __launch_bounds__(512, 4) void kA_scores(
    const unsigned short* __restrict__ Qg, const unsigned short* __restrict__ Kg,
    unsigned short* __restrict__ Pg, float* __restrict__ sbuf,
    int b0, int bshift){
  const int wg = blockIdx.x;
  const int bmask = (1 << bshift) - 1;
  const int b = b0 + (wg & bmask);
  const int q0 = (wg >> bshift) * 32;
  const int tid = threadIdx.x, lane = tid & 63, w = tid >> 6;
  const int l15 = lane & 15, g = lane >> 4;
  __shared__ float wsum[32][8];
  const unsigned short* Qb = Qg + (size_t)b * 2048 * 64;
  const unsigned short* Kb = Kg + (size_t)b * 2048 * 64;
  unsigned short* Pb = Pg + (size_t)(wg & bmask) * 2048 * 2048;

  short8 qf[2][2];
  #pragma unroll
  for (int qi = 0; qi < 2; qi++)
    #pragma unroll
    for (int kc = 0; kc < 2; kc++)
      qf[qi][kc] = *(const short8*)(Qb + (size_t)(q0 + qi * 16 + l15) * 64 + kc * 32 + g * 8);

  float ps[2] = {0.f, 0.f};                   // per-lane partial for q = qi*16+l15

  const int wm0 = w * 256;
  #pragma unroll
  for (int mt = 0; mt < 4; ++mt){
    const int mb = wm0 + mt * 64;
    short8 kf[4][2];
    #pragma unroll
    for (int mi = 0; mi < 4; mi++)
      #pragma unroll
      for (int kc = 0; kc < 2; kc++)
        kf[mi][kc] = *(const short8*)(Kb + (size_t)(mb + mi * 16 + l15) * 64 + kc * 32 + g * 8);
    #pragma unroll
    for (int qi = 0; qi < 2; qi++){
      f32x4 sa[4];
      #pragma unroll
      for (int mi = 0; mi < 4; mi++) sa[mi] = (f32x4){0.f,0.f,0.f,0.f};
      #pragma unroll
      for (int mi = 0; mi < 4; mi++)
        #pragma unroll
        for (int kc = 0; kc < 2; kc++)
          sa[mi] = __builtin_amdgcn_mfma_f32_16x16x32_bf16(kf[mi][kc], qf[qi][kc], sa[mi], 0, 0, 0);
      #pragma unroll
      for (int mi = 0; mi < 4; mi++){
        short4v pk;
        #pragma unroll
        for (int r = 0; r < 4; r++){
          float p = __expf(sa[mi][r]);        // sa[mi][r] = S[m=mb+mi*16+g*4+r][q]
          ps[qi] += p;
          pk[r] = (short)f2bf(p);
        }
        *(short4v*)(Pb + (size_t)(q0 + qi * 16 + l15) * 2048 + mb + mi * 16 + g * 4) = pk;
      }
    }
  }
  #pragma unroll
  for (int qi = 0; qi < 2; qi++){
    float t = ps[qi];
    t += __shfl_xor(t, 16);
    t += __shfl_xor(t, 32);                   // sum over the 4 g-groups
    if (lane < 16) wsum[qi * 16 + l15][w] = t;
  }
  __syncthreads();
  if (tid < 32){
    float t = 0.f;
    #pragma unroll
    for (int i = 0; i < 8; i++) t += wsum[tid][i];
    sbuf[(size_t)b * 2048 + q0 + tid] = t;
  }
}

// ---------------- kB v5: O = P@V^T; async global_load_lds staging ----------------
// grid 64*nb (b; oh = o-half; nt -> 64 n-rows). LDS dbuf 2x24KB. Staging: per
// wave 6 x global_load_lds(16B/lane): LDS dest = uniform base + lane*16
// (linear), global source pre-swizzled (col ^ (row&7)<<4) -> read-side XOR
// unchanged. One barrier/chunk drains vmcnt. 3 WG/CU.
__global__ __launch_bounds__(256, 3) void kB_pv(
    const unsigned short* __restrict__ Pg, const unsigned short* __restrict__ Vt,
    const float* __restrict__ sbuf, unsigned* __restrict__ tmaxe,
    int b0, int bshift){
  const int wg = blockIdx.x;
  const int bmask = (1 << bshift) - 1;
  const int b = b0 + (wg & bmask);
  const int rest = wg >> bshift;
  const int oh = rest & 1;
  const int n0 = (rest >> 1) * 64;
  const int tid = threadIdx.x, lane = tid & 63, w = tid >> 6;
  const int l15 = lane & 15, g = lane >> 4;
  __shared__ __align__(16) unsigned char smem[2][24576];  // dbuf: Pl 8KB | Vl 16KB

  const unsigned short* Pb = Pg + (size_t)(wg & bmask) * 2048 * 2048;
  const unsigned short* Vb = Vt + ((size_t)b * 256 + oh * 128) * 2048;

  f32x4 acc[4][2];
  #pragma unroll
  for (int ni = 0; ni < 4; ni++)
    #pragma unroll
    for (int oi = 0; oi < 2; oi++) acc[ni][oi] = (f32x4){0.f,0.f,0.f,0.f};

  // per-lane source precompute: d = k*4096 + w*1024 + lane*16
  // k<2 (P): row = d>>7 in [0,64), srcP = Pb[(n0+row)*2048 + (colB^swz)/1]
  // k>=2 (V): dv = d-8192, row in [0,128)
  const unsigned short* psrc[6];
  {
    #pragma unroll
    for (int k = 0; k < 6; k++){
      int d = k * 4096 + w * 1024 + lane * 16;
      if (k < 2){
        int row = d >> 7;
        int colB = (d & 127) ^ ((row & 7) << 4);
        psrc[k] = Pb + (size_t)(n0 + row) * 2048 + (colB >> 1);
      } else {
        int dv = d - 8192;
        int row = dv >> 7;
        int colB = (dv & 127) ^ ((row & 7) << 4);
        psrc[k] = Vb + (size_t)row * 2048 + (colB >> 1);
      }
    }
  }
  auto ISSUE = [&](int m0, int bufIdx){
    #pragma unroll
    for (int k = 0; k < 6; k++){
      unsigned char* dst = &smem[bufIdx][k * 4096 + w * 1024];  // wave-uniform
      __builtin_amdgcn_global_load_lds(
          (const __attribute__((address_space(1))) void*)(psrc[k] + m0),
          (__attribute__((address_space(3))) void*)dst, 16, 0, 0);
    }
  };

  ISSUE(0, 0);
  __syncthreads();                                     // drains vmcnt: buf0 ready

  for (int t = 0; t < 32; ++t){
    unsigned char* cur = smem[t & 1];
    if (t < 31) ISSUE((t + 1) * 64, (t + 1) & 1);      // async into other buffer
    short8 af[4][2], bf[2][2];
    #pragma unroll
    for (int ni = 0; ni < 4; ni++)
      #pragma unroll
      for (int kc = 0; kc < 2; kc++){
        int row = ni * 16 + l15;
        af[ni][kc] = *(const short8*)(cur + ((row * 128 + kc * 64 + g * 16) ^ ((row & 7) << 4)));
      }
    #pragma unroll
    for (int oi = 0; oi < 2; oi++)
      #pragma unroll
      for (int kc = 0; kc < 2; kc++){
        int row = w * 32 + oi * 16 + l15;
        bf[oi][kc] = *(const short8*)(cur + 8192 + ((row * 128 + kc * 64 + g * 16) ^ ((row & 7) << 4)));
      }
    #pragma unroll
    for (int ni = 0; ni < 4; ni++)
      #pragma unroll
      for (int oi = 0; oi < 2; oi++)
        #pragma unroll
        for (int kc = 0; kc < 2; kc++)
          acc[ni][oi] = __builtin_amdgcn_mfma_f32_16x16x32_bf16(af[ni][kc], bf[oi][kc], acc[ni][oi], 0, 0, 0);
    if (t < 31)
      __syncthreads();                                 // next buf ready; cur reads done
  }
  float inv[4][4];
  #pragma unroll
  for (int ni = 0; ni < 4; ni++)
    #pragma unroll
    for (int r = 0; r < 4; r++)
      inv[ni][r] = 1.0f / sbuf[(size_t)b * 2048 + n0 + ni * 16 + g * 4 + r];
  #pragma unroll
  for (int oi = 0; oi < 2; oi++){
    float cm = -1e30f;
    #pragma unroll
    for (int ni = 0; ni < 4; ni++)
      #pragma unroll
      for (int r = 0; r < 4; r++)
        cm = fmaxf(cm, acc[ni][oi][r] * inv[ni][r]);
    cm = fmaxf(cm, __shfl_xor(cm, 16));
    cm = fmaxf(cm, __shfl_xor(cm, 32));
    if (lane < 16)
      atomicMax(&tmaxe[b * 256 + oh * 128 + w * 32 + oi * 16 + lane], fenc(cm));
  }
}

// ---------------- K5: W_eff = P0 + P1*t + P2 (bf16); bias_eff; w0/w1 -> bf16 -----
__global__ __launch_bounds__(256) void k5_weff(const float* __restrict__ proj_w,
    const float* __restrict__ proj_b, const unsigned* __restrict__ tmaxe,
    const float* __restrict__ params, unsigned short* __restrict__ weff,
    float* __restrict__ beff, unsigned short* __restrict__ w0b,
    unsigned short* __restrict__ w1b){
  const int b = blockIdx.y, o = blockIdx.x;
  const int c = threadIdx.x;                  // 256
  float t = fdec(tmaxe[b * 256 + c]);
  float p0 = proj_w[o * 768 + c];
  float p1 = proj_w[o * 768 + 256 + c];
  float p2 = proj_w[o * 768 + 512 + c];
  weff[((size_t)b * 64 + o) * 256 + c] = f2bf(p0 + p1 * t + p2);
  float s = p0 * t;
  #pragma unroll
  for (int d = 1; d < 64; d <<= 1) s += __shfl_xor(s, d);
  __shared__ float sm[4];
  if ((c & 63) == 0) sm[c >> 6] = s;
  __syncthreads();
  if (c == 0) beff[b * 64 + o] = proj_b[o] - (sm[0] + sm[1] + sm[2] + sm[3]);
  if (c < 64)        w0b[((size_t)b * 64 + o) * 64 + c] = f2bf(params[b * 8385 + o * 64 + c]);
  else if (c < 128)  w1b[((size_t)b * 64 + o) * 64 + (c - 64)] = f2bf(params[b * 8385 + 4096 + o * 64 + (c - 64)]);
}

// ---------------- K6: fused scene pipeline (scene read exactly once) -------------
__global__ __launch_bounds__(512) void k6_main(const float* __restrict__ Sg,
    const unsigned short* __restrict__ weff, const float* __restrict__ beff,
    const unsigned short* __restrict__ w0b, const unsigned short* __restrict__ w1b,
    const float* __restrict__ params, float* __restrict__ out){
  const int b = blockIdx.y, nt = blockIdx.x;
  const int n0 = nt * 256;
  const int tid = threadIdx.x, lane = tid & 63, w = tid >> 6;
  const int l15 = lane & 15, g = lane >> 4;
  __shared__ __align__(16) unsigned char smem[65536];
  unsigned short* H0 = (unsigned short*)smem;            // [n][64] XOR-swizzled, 32 KB
  unsigned char*  Ub = smem + 32768;                     // Bs32 (16KB) then H1 (32KB)
  unsigned short* H1 = (unsigned short*)Ub;

  const float* Sb = Sg + (size_t)b * 256 * 16384;
  const unsigned short* We = weff + (size_t)b * 64 * 256;
  f32x4 a0[4][2];
  #pragma unroll
  for (int mi = 0; mi < 4; mi++)
    #pragma unroll
    for (int ni = 0; ni < 2; ni++) a0[mi][ni] = (f32x4){0.f,0.f,0.f,0.f};

  const int scc = tid & 31;                   // c row within k-tile
  const int snb = (tid >> 5) * 16;            // 16 n per thread
  const float* src0 = Sb + (size_t)scc * 16384 + n0 + snb;
  float4 v0 = ((const float4*)src0)[0];
  float4 v1 = ((const float4*)src0)[1];
  float4 v2 = ((const float4*)src0)[2];
  float4 v3 = ((const float4*)src0)[3];
  for (int k0 = 0; k0 < 256; k0 += 32){
    float vals[16] = {v0.x,v0.y,v0.z,v0.w, v1.x,v1.y,v1.z,v1.w,
                      v2.x,v2.y,v2.z,v2.w, v3.x,v3.y,v3.z,v3.w};
    #pragma unroll
    for (int j = 0; j < 16; j++){
      int n = snb + j;
      unsigned byteo = ((unsigned)(n * 64 + scc * 2)) ^ ((unsigned)((n >> 1) & 3) << 4);
      *(unsigned short*)(Ub + byteo) = f2bf(vals[j]);
    }
    if (k0 < 224){                            // prefetch next k-tile into regs
      const float* nsrc = Sb + (size_t)(k0 + 32 + scc) * 16384 + n0 + snb;
      v0 = ((const float4*)nsrc)[0];
      v1 = ((const float4*)nsrc)[1];
      v2 = ((const float4*)nsrc)[2];
      v3 = ((const float4*)nsrc)[3];
    }
    __syncthreads();
    short8 bf0[2];
    #pragma unroll
    for (int ni = 0; ni < 2; ni++){
      int n = w * 32 + ni * 16 + l15;
      bf0[ni] = *(const short8*)(Ub + (((unsigned)(n * 64 + g * 16)) ^ ((unsigned)((n >> 1) & 3) << 4)));
    }
    #pragma unroll
    for (int mi = 0; mi < 4; mi++){
      short8 af = *(const short8*)(We + (mi * 16 + l15) * 256 + k0 + g * 8);
      #pragma unroll
      for (int ni = 0; ni < 2; ni++)
        a0[mi][ni] = __builtin_amdgcn_mfma_f32_16x16x32_bf16(af, bf0[ni], a0[mi][ni], 0, 0, 0);
    }
    __syncthreads();
  }
  const float* be = beff + b * 64;
  #pragma unroll
  for (int mi = 0; mi < 4; mi++)
    #pragma unroll
    for (int ni = 0; ni < 2; ni++){
      int n = w * 32 + ni * 16 + l15;
      unsigned base = ((unsigned)(n * 128 + mi * 32 + g * 8)) ^ ((unsigned)((n & 7) << 4));
      unsigned short hh[4];
      #pragma unroll
      for (int r = 0; r < 4; r++){
        int o = mi * 16 + g * 4 + r;
        hh[r] = f2bf(fmaxf(a0[mi][ni][r] + be[o], 0.f));
      }
      *(unsigned*)((unsigned char*)H0 + base)     = (unsigned)hh[0] | ((unsigned)hh[1] << 16);
      *(unsigned*)((unsigned char*)H0 + base + 4) = (unsigned)hh[2] | ((unsigned)hh[3] << 16);
    }
  __syncthreads();
  f32x4 a1[4][2];
  #pragma unroll
  for (int mi = 0; mi < 4; mi++)
    #pragma unroll
    for (int ni = 0; ni < 2; ni++) a1[mi][ni] = (f32x4){0.f,0.f,0.f,0.f};
  const unsigned short* W0 = w0b + (size_t)b * 4096;
  #pragma unroll
  for (int ks = 0; ks < 2; ks++){
    short8 bfh[2];
    #pragma unroll
    for (int ni = 0; ni < 2; ni++){
      int n = w * 32 + ni * 16 + l15;
      unsigned off = ((unsigned)(n * 128 + ks * 64 + g * 16)) ^ ((unsigned)((n & 7) << 4));
      bfh[ni] = *(const short8*)((unsigned char*)H0 + off);
    }
    #pragma unroll
    for (int mi = 0; mi < 4; mi++){
      short8 af = *(const short8*)(W0 + (mi * 16 + l15) * 64 + ks * 32 + g * 8);
      #pragma unroll
      for (int ni = 0; ni < 2; ni++)
        a1[mi][ni] = __builtin_amdgcn_mfma_f32_16x16x32_bf16(af, bfh[ni], a1[mi][ni], 0, 0, 0);
    }
  }
  const float* pp = params + (size_t)b * 8385;
  const float* b0p = pp + 8256;
  #pragma unroll
  for (int mi = 0; mi < 4; mi++)
    #pragma unroll
    for (int ni = 0; ni < 2; ni++){
      int n = w * 32 + ni * 16 + l15;
      unsigned base = ((unsigned)(n * 128 + mi * 32 + g * 8)) ^ ((unsigned)((n & 7) << 4));
      unsigned short hh[4];
      #pragma unroll
      for (int r = 0; r < 4; r++){
        int o = mi * 16 + g * 4 + r;
        hh[r] = f2bf(fmaxf(a1[mi][ni][r] + b0p[o], 0.f));
      }
      *(unsigned*)((unsigned char*)H1 + base)     = (unsigned)hh[0] | ((unsigned)hh[1] << 16);
      *(unsigned*)((unsigned char*)H1 + base + 4) = (unsigned)hh[2] | ((unsigned)hh[3] << 16);
    }
  __syncthreads();
  f32x4 a2[4][2];
  #pragma unroll
  for (int mi = 0; mi < 4; mi++)
    #pragma unroll
    for (int ni = 0; ni < 2; ni++) a2[mi][ni] = (f32x4){0.f,0.f,0.f,0.f};
  const unsigned short* W1 = w1b + (size_t)b * 4096;
  #pragma unroll
  for (int ks = 0; ks < 2; ks++){
    short8 bfh[2];
    #pragma unroll
    for (int ni = 0; ni < 2; ni++){
      int n = w * 32 + ni * 16 + l15;
      unsigned off = ((unsigned)(n * 128 + ks * 64 + g * 16)) ^ ((unsigned)((n & 7) << 4));
      bfh[ni] = *(const short8*)((unsigned char*)H1 + off);
    }
    #pragma unroll
    for (int mi = 0; mi < 4; mi++){
      short8 af = *(const short8*)(W1 + (mi * 16 + l15) * 64 + ks * 32 + g * 8);
      #pragma unroll
      for (int ni = 0; ni < 2; ni++)
        a2[mi][ni] = __builtin_amdgcn_mfma_f32_16x16x32_bf16(af, bfh[ni], a2[mi][ni], 0, 0, 0);
    }
  }
  const float* b1p = pp + 8320;
  const float* w2p = pp + 8192;
  float b2v = pp[8384];
  #pragma unroll
  for (int ni = 0; ni < 2; ni++){
    float t = 0.f;
    #pragma unroll
    for (int mi = 0; mi < 4; mi++)
      #pragma unroll
      for (int r = 0; r < 4; r++){
        int o = mi * 16 + g * 4 + r;
        t += w2p[o] * fmaxf(a2[mi][ni][r] + b1p[o], 0.f);
      }
    t += __shfl_xor(t, 16);
    t += __shfl_xor(t, 32);
    if (lane < 16)
      out[(size_t)b * 16384 + n0 + w * 32 + ni * 16 + l15] = t + b2v;
  }
}

extern "C" void kernel_launch(void* const* d_in, const int* in_sizes, int n_in,
                              void* d_out, int out_size, void* d_ws, size_t ws_size,
                              hipStream_t stream){
  const float* scene = (const float*)d_in[0];
  const float* tmpl  = (const float*)d_in[1];
  const float* qw    = (const float*)d_in[2];
  const float* kw    = (const float*)d_in[3];
  const float* vw    = (const float*)d_in[4];
  const float* pw    = (const float*)d_in[5];
  const float* pb    = (const float*)d_in[6];
  const float* cw    = (const float*)d_in[7];
  const float* cb    = (const float*)d_in[8];
  float* out = (float*)d_out;
  char* ws = (char*)d_ws;

  unsigned short* Q      = (unsigned short*)(ws + 0);                    // 2 MB
  unsigned short* K      = (unsigned short*)(ws + (2u << 20));           // 2 MB
  unsigned short* V      = (unsigned short*)(ws + (4u << 20));           // 8 MB
  unsigned*       pooledEnc = (unsigned*)(ws + (12u << 20));             // 8 KB
  unsigned*       tmaxe  = (unsigned*)(ws + (12u << 20) + 8192);         // 8 KB
  float*          params = (float*)(ws + (12u << 20) + 16384);           // 268 KB
  unsigned short* w0b    = (unsigned short*)(ws + (13u << 20));          // 64 KB
  unsigned short* w1b    = (unsigned short*)(ws + (13u << 20) + 65536);  // 64 KB
  unsigned short* weff   = (unsigned short*)(ws + (13u << 20) + 131072); // 256 KB
  float*          beff   = (float*)(ws + (13u << 20) + 131072 + 262144); // 2 KB
  float*          sbuf   = (float*)(ws + (14u << 20));                   // 64 KB
  unsigned short* Wbf    = (unsigned short*)(ws + (14u << 20) + 131072); // 192 KB
  unsigned short* Pbuf   = (unsigned short*)(ws + (16u << 20));          // up to 67 MB
  unsigned short* Tt     = Pbuf;   // 8 MB; dead before kA writes Pbuf (stream order)

  const size_t pPerBatch = (size_t)2048 * 2048 * 2;
  size_t avail = ws_size > (16u << 20) ? ws_size - (16u << 20) : 0;
  int nb = 8, bshift = 3;
  while (nb > 1 && (size_t)nb * pPerBatch > avail){ nb >>= 1; bshift--; }

  k0w<<<dim3(96), dim3(256), 0, stream>>>(qw, kw, vw, Wbf, tmaxe, pooledEnc);
  k0_tt<<<dim3(8, 16, 8), dim3(256), 0, stream>>>(tmpl, Tt, pooledEnc);
  k23_qkv_params<<<dim3(512 + 2097), dim3(256), 0, stream>>>(Wbf, Tt, Q, K, V,
                                                             pooledEnc, cw, cb, params);
  for (int b0 = 0; b0 < 8; b0 += nb){
    kA_scores<<<dim3(64 * nb), dim3(512), 0, stream>>>(Q, K, Pbuf, sbuf, b0, bshift);
    kB_pv<<<dim3(64 * nb), dim3(256), 0, stream>>>(Pbuf, V, sbuf, tmaxe, b0, bshift);
  }
  k5_weff<<<dim3(64, 8), dim3(256), 0, stream>>>(pw, pb, tmaxe, params, weff, beff, w0b, w1b);
  k6_main<<<dim3(64, 8), dim3(512), 0, stream>>>(scene, weff, beff, w0b, w1b, params, out);
}

// Round 14
// 140.111 us; speedup vs baseline: 1.2548x; 1.0020x over previous
//
#include <hip/hip_runtime.h>
#include <hip/hip_fp8.h>

// DynamicConvolution fused pipeline for MI355X (gfx950).
// R14 (base = R13, 140.4): P and V stored as FP8 e4m3 for the PV GEMM.
// kA packs 4 fp8/lane (u32 stores, 67->34MB P write); kB uses
// mfma_f32_16x16x32_fp8_fp8 with i64 frags (k-map shared by A/B => safe),
// LDS dbuf 2x12KB (4 WG/CU), 3 global_load_lds/lane with 16B-granule
// source pre-swizzle (row&3)<<4. s stays f32 from unquantized p. k23 emits V
// in fp8 directly. Everything else identical to R13.
// Stages: k0w -> k0_tt -> k23 qkv+params -> kA exp(QK^T) -> kB PV+tmax ->
//         k5 W_eff -> k6 fused scene MLP.

typedef __attribute__((ext_vector_type(8))) short short8;
typedef __attribute__((ext_vector_type(4))) short short4v;
typedef __attribute__((ext_vector_type(4))) float f32x4;

__device__ __forceinline__ unsigned short f2bf(float f){
  unsigned u = __float_as_uint(f);
  u += 0x7FFFu + ((u >> 16) & 1u);           // round-to-nearest-even
  return (unsigned short)(u >> 16);
}
__device__ __forceinline__ unsigned char f2e4m3(float f){
  return __hip_fp8_e4m3(f).__x;              // OCP e4m3 (gfx950 HW format)
}
// monotone float<->uint for atomicMax on floats (incl. negatives)
__device__ __forceinline__ unsigned fenc(float f){
  unsigned u = __float_as_uint(f);
  return (u & 0x80000000u) ? ~u : (u | 0x80000000u);
}
__device__ __forceinline__ float fdec(unsigned k){
  unsigned u = (k & 0x80000000u) ? (k & 0x7FFFFFFFu) : ~k;
  return __uint_as_float(u);
}

// ---------------- k0w: Wbf[384][256] bf16 (q*0.125 folded); init tmaxe/pooledEnc -
__global__ __launch_bounds__(256) void k0w(const float* __restrict__ qw,
    const float* __restrict__ kw, const float* __restrict__ vw,
    unsigned short* __restrict__ Wbf, unsigned* __restrict__ tmaxe,
    unsigned* __restrict__ pooledEnc){
  if (blockIdx.x == 0){
    const unsigned ninf = fenc(-3.0e38f);
    for (int i = threadIdx.x; i < 2048; i += 256){
      tmaxe[i] = 0u;                          // floor for encoded O-max
      pooledEnc[i] = ninf;                    // true -inf floor for pooled max
    }
  }
  const int e = (blockIdx.x * 256 + threadIdx.x) * 4;   // 96 WGs * 1024 = 98304
  const int row = e >> 8, c = e & 255;
  const float* src;
  float scl = 1.0f;
  if (row < 64){ src = qw + row * 256 + c; scl = 0.125f; }
  else if (row < 128){ src = kw + (row - 64) * 256 + c; }
  else { src = vw + (row - 128) * 256 + c; }
  float4 v = *(const float4*)src;
  short4v o;
  o[0] = (short)f2bf(v.x * scl); o[1] = (short)f2bf(v.y * scl);
  o[2] = (short)f2bf(v.z * scl); o[3] = (short)f2bf(v.w * scl);
  *(short4v*)(Wbf + e) = o;
}

// ---------------- k0_tt: Tt[b][n][c] = bf16(T[b][c][n]); pooled max fold ---------
__global__ __launch_bounds__(256) void k0_tt(const float* __restrict__ T,
    unsigned short* __restrict__ Tt, unsigned* __restrict__ pooledEnc){
  const int b = blockIdx.x, nt = blockIdx.y, ct = blockIdx.z;
  const int n0 = nt * 128, c0 = ct * 32;
  const int tid = threadIdx.x;
  __shared__ float Ls[32][129];
  const int cr = tid >> 3, nq = tid & 7;      // 32 c-rows x 8 n-chunks(16 f32)
  const float* src = T + ((size_t)b * 256 + c0 + cr) * 2048 + n0 + nq * 16;
  float4 v0 = ((const float4*)src)[0];
  float4 v1 = ((const float4*)src)[1];
  float4 v2 = ((const float4*)src)[2];
  float4 v3 = ((const float4*)src)[3];
  float mx = fmaxf(fmaxf(fmaxf(v0.x, v0.y), fmaxf(v0.z, v0.w)),
                   fmaxf(fmaxf(v1.x, v1.y), fmaxf(v1.z, v1.w)));
  mx = fmaxf(mx, fmaxf(fmaxf(fmaxf(v2.x, v2.y), fmaxf(v2.z, v2.w)),
                       fmaxf(fmaxf(v3.x, v3.y), fmaxf(v3.z, v3.w))));
  mx = fmaxf(mx, __shfl_xor(mx, 1));
  mx = fmaxf(mx, __shfl_xor(mx, 2));
  mx = fmaxf(mx, __shfl_xor(mx, 4));
  if (nq == 0) atomicMax(&pooledEnc[b * 256 + c0 + cr], fenc(mx));
  float* lr = &Ls[cr][nq * 16];
  *(float4*)lr = v0; *(float4*)(lr + 4) = v1;
  *(float4*)(lr + 8) = v2; *(float4*)(lr + 12) = v3;
  __syncthreads();
  const int nr = tid >> 1, ch = tid & 1;      // 128 n-rows x 2 c-halves(16)
  unsigned short ob[16];
  #pragma unroll
  for (int j = 0; j < 16; j++) ob[j] = f2bf(Ls[ch * 16 + j][nr]);
  unsigned short* dst = Tt + ((size_t)b * 2048 + n0 + nr) * 256 + c0 + ch * 16;
  *(short8*)dst = *(short8*)&ob[0];
  *(short8*)(dst + 8) = *(short8*)&ob[8];
}

// ---------------- k23: fused k2 (QKV gemm, wg<512) + k3 (params gemv) ------------
// V output now fp8 e4m3: vt8[b][o][n] (1 B/elem), packed u32 stores.
__global__ __launch_bounds__(256) void k23_qkv_params(
    const unsigned short* __restrict__ Wbf, const unsigned short* __restrict__ Tt,
    unsigned short* __restrict__ qo, unsigned short* __restrict__ ko,
    unsigned char* __restrict__ vt8,
    const unsigned* __restrict__ pooledEnc, const float* __restrict__ cw,
    const float* __restrict__ cb, float* __restrict__ params){
  const int wg = blockIdx.x;
  const int tid = threadIdx.x, lane = tid & 63, w = tid >> 6;
  if (wg >= 512){
    // ---- k3 body: params[b][r] = pooled[b].cw[r] + cb[r]
    __shared__ float P[8 * 256];
    for (int i = tid; i < 2048; i += 256) P[i] = fdec(pooledEnc[i]);
    __syncthreads();
    const int r = (wg - 512) * 4 + w;
    if (r >= 8385) return;
    float4 c4 = ((const float4*)(cw + (size_t)r * 256))[lane];
    float bias = cb[r];
    #pragma unroll
    for (int b = 0; b < 8; b++){
      const float* pbp = P + b * 256 + lane * 4;
      float s = c4.x * pbp[0] + c4.y * pbp[1] + c4.z * pbp[2] + c4.w * pbp[3];
      #pragma unroll
      for (int d = 1; d < 64; d <<= 1) s += __shfl_xor(s, d);
      if (lane == 0) params[b * 8385 + r] = s + bias;
    }
    return;
  }
  // ---- k2 body (R5-proven): no LDS, direct global frags
  const int b = wg & 7, nt = wg >> 3;
  const int n0 = nt * 32;
  const int l15 = lane & 15, g = lane >> 4;
  const unsigned short* Tb = Tt + (size_t)b * 2048 * 256;

  f32x4 aqk[2][2], av[4][2];
  #pragma unroll
  for (int i = 0; i < 2; i++)
    #pragma unroll
    for (int nf = 0; nf < 2; nf++) aqk[i][nf] = (f32x4){0.f,0.f,0.f,0.f};
  #pragma unroll
  for (int j = 0; j < 4; j++)
    #pragma unroll
    for (int nf = 0; nf < 2; nf++) av[j][nf] = (f32x4){0.f,0.f,0.f,0.f};

  #pragma unroll 2
  for (int kc = 0; kc < 8; kc++){
    short8 bfr[2];
    #pragma unroll
    for (int nf = 0; nf < 2; nf++)
      bfr[nf] = *(const short8*)(Tb + (size_t)(n0 + nf * 16 + l15) * 256 + kc * 32 + g * 8);
    short8 aq[2];
    #pragma unroll
    for (int i = 0; i < 2; i++)
      aq[i] = *(const short8*)(Wbf + (size_t)((2 * w + i) * 16 + l15) * 256 + kc * 32 + g * 8);
    short8 afv[4];
    #pragma unroll
    for (int j = 0; j < 4; j++)
      afv[j] = *(const short8*)(Wbf + (size_t)(128 + (4 * w + j) * 16 + l15) * 256 + kc * 32 + g * 8);
    #pragma unroll
    for (int i = 0; i < 2; i++)
      #pragma unroll
      for (int nf = 0; nf < 2; nf++)
        aqk[i][nf] = __builtin_amdgcn_mfma_f32_16x16x32_bf16(aq[i], bfr[nf], aqk[i][nf], 0, 0, 0);
    #pragma unroll
    for (int j = 0; j < 4; j++)
      #pragma unroll
      for (int nf = 0; nf < 2; nf++)
        av[j][nf] = __builtin_amdgcn_mfma_f32_16x16x32_bf16(bfr[nf], afv[j], av[j][nf], 0, 0, 0);
  }
  unsigned short* qk = (w < 2) ? qo : ko;
  #pragma unroll
  for (int i = 0; i < 2; i++)
    #pragma unroll
    for (int nf = 0; nf < 2; nf++){
      int n = n0 + nf * 16 + l15;
      int cbase = (w & 1) * 32 + i * 16 + g * 4;
      short4v pk;
      #pragma unroll
      for (int r = 0; r < 4; r++) pk[r] = (short)f2bf(aqk[i][nf][r]);
      *(short4v*)(qk + ((size_t)b * 2048 + n) * 64 + cbase) = pk;
    }
  #pragma unroll
  for (int j = 0; j < 4; j++)
    #pragma unroll
    for (int nf = 0; nf < 2; nf++){
      int o = (4 * w + j) * 16 + l15;
      int nb2 = n0 + nf * 16 + g * 4;
      unsigned pv8 = 0;
      #pragma unroll
      for (int r = 0; r < 4; r++)
        pv8 |= (unsigned)f2e4m3(av[j][nf][r]) << (8 * r);
      *(unsigned*)(vt8 + ((size_t)b * 256 + o) * 2048 + nb2) = pv8;
    }
}

// ---------------- kA v5: swapped QK -> P fp8 row-major [q][2048] -----------------
// Lane holds 4 consecutive m for one q -> one packed-u32 fp8 store per tile.
// s computed in f32 from UNQUANTIZED p.
__global__ __launch_bounds__(512, 4) void kA_scores(
    const unsigned short* __restrict__ Qg, const unsigned short* __restrict__ Kg,
    unsigned char* __restrict__ Pg, float* __restrict__ sbuf,
    int b0, int bshift){
  const int wg = blockIdx.x;
  const int bmask = (1 << bshift) - 1;
  const int b = b0 + (wg & bmask);
  const int q0 = (wg >> bshift) * 32;
  const int tid = threadIdx.x, lane = tid & 63, w = tid >> 6;
  const int l15 = lane & 15, g = lane >> 4;
  __shared__ float wsum[32][8];
  const unsigned short* Qb = Qg + (size_t)b * 2048 * 64;
  const unsigned short* Kb = Kg + (size_t)b * 2048 * 64;
  unsigned char* Pb = Pg + (size_t)(wg & bmask) * 2048 * 2048;

  short8 qf[2][2];
  #pragma unroll
  for (int qi = 0; qi < 2; qi++)
    #pragma unroll
    for (int kc = 0; kc < 2; kc++)
      qf[qi][kc] = *(const short8*)(Qb + (size_t)(q0 + qi * 16 + l15) * 64 + kc * 32 + g * 8);

  float ps[2] = {0.f, 0.f};                   // per-lane partial for q = qi*16+l15

  const int wm0 = w * 256;
  #pragma unroll
  for (int mt = 0; mt < 4; ++mt){
    const int mb = wm0 + mt * 64;
    short8 kf[4][2];
    #pragma unroll
    for (int mi = 0; mi < 4; mi++)
      #pragma unroll
      for (int kc = 0; kc < 2; kc++)
        kf[mi][kc] = *(const short8*)(Kb + (size_t)(mb + mi * 16 + l15) * 64 + kc * 32 + g * 8);
    #pragma unroll
    for (int qi = 0; qi < 2; qi++){
      f32x4 sa[4];
      #pragma unroll
      for (int mi = 0; mi < 4; mi++) sa[mi] = (f32x4){0.f,0.f,0.f,0.f};
      #pragma unroll
      for (int mi = 0; mi < 4; mi++)
        #pragma unroll
        for (int kc = 0; kc < 2; kc++)
          sa[mi] = __builtin_amdgcn_mfma_f32_16x16x32_bf16(kf[mi][kc], qf[qi][kc], sa[mi], 0, 0, 0);
      #pragma unroll
      for (int mi = 0; mi < 4; mi++){
        unsigned pk8 = 0;
        #pragma unroll
        for (int r = 0; r < 4; r++){
          float p = __expf(sa[mi][r]);        // sa[mi][r] = S[m=mb+mi*16+g*4+r][q]
          ps[qi] += p;
          pk8 |= (unsigned)f2e4m3(p) << (8 * r);
        }
        *(unsigned*)(Pb + (size_t)(q0 + qi * 16 + l15) * 2048 + mb + mi * 16 + g * 4) = pk8;
      }
    }
  }
  #pragma unroll
  for (int qi = 0; qi < 2; qi++){
    float t = ps[qi];
    t += __shfl_xor(t, 16);
    t += __shfl_xor(t, 32);                   // sum over the 4 g-groups
    if (lane < 16) wsum[qi * 16 + l15][w] = t;
  }
  __syncthreads();
  if (tid < 32){
    float t = 0.f;
    #pragma unroll
    for (int i = 0; i < 8; i++) t += wsum[tid][i];
    sbuf[(size_t)b * 2048 + q0 + tid] = t;
  }
}

// ---------------- kB v6: O = P8@V8^T via fp8 MFMA; async LDS staging -------------
// grid 64*nb (b; oh = o-half; nt -> 64 n-rows). LDS dbuf 2x12KB (P 4KB + V 8KB,
// fp8). 3 x global_load_lds(16B)/lane, source pre-swizzled (col^(row&3)<<4,
// 16B granule). Frags: i64 (8 fp8), mfma_f32_16x16x32_fp8_fp8 x2 per chunk
// pair (kc). A/B share the byte->m map => k-perm safe. 4 WG/CU.
__global__ __launch_bounds__(256, 4) void kB_pv(
    const unsigned char* __restrict__ Pg, const unsigned char* __restrict__ Vt,
    const float* __restrict__ sbuf, unsigned* __restrict__ tmaxe,
    int b0, int bshift){
  const int wg = blockIdx.x;
  const int bmask = (1 << bshift) - 1;
  const int b = b0 + (wg & bmask);
  const int rest = wg >> bshift;
  const int oh = rest & 1;
  const int n0 = (rest >> 1) * 64;
  const int tid = threadIdx.x, lane = tid & 63, w = tid >> 6;
  const int l15 = lane & 15, g = lane >> 4;
  __shared__ __align__(16) unsigned char smem[2][12288];  // dbuf: Pl 4KB | Vl 8KB

  const unsigned char* Pb = Pg + (size_t)(wg & bmask) * 2048 * 2048;
  const unsigned char* Vb = Vt + ((size_t)b * 256 + oh * 128) * 2048;

  f32x4 acc[4][2];
  #pragma unroll
  for (int ni = 0; ni < 4; ni++)
    #pragma unroll
    for (int oi = 0; oi < 2; oi++) acc[ni][oi] = (f32x4){0.f,0.f,0.f,0.f};

  // per-lane pre-swizzled sources: d = k*4096 + w*1024 + lane*16
  const unsigned char* psrc[3];
  {
    #pragma unroll
    for (int k = 0; k < 3; k++){
      int d = k * 4096 + w * 1024 + lane * 16;
      if (k < 1){                                        // P: 64 rows x 64B
        int row = d >> 6;
        int colB = (d & 63) ^ ((row & 3) << 4);
        psrc[k] = Pb + (size_t)(n0 + row) * 2048 + colB;
      } else {                                           // V-half: 128 rows x 64B
        int dv = d - 4096;
        int row = dv >> 6;
        int colB = (dv & 63) ^ ((row & 3) << 4);
        psrc[k] = Vb + (size_t)row * 2048 + colB;
      }
    }
  }
  auto ISSUE = [&](int m0, int bufIdx){
    #pragma unroll
    for (int k = 0; k < 3; k++){
      unsigned char* dst = &smem[bufIdx][k * 4096 + w * 1024];  // wave-uniform
      __builtin_amdgcn_global_load_lds(
          (const __attribute__((address_space(1))) void*)(psrc[k] + m0),
          (__attribute__((address_space(3))) void*)dst, 16, 0, 0);
    }
  };

  ISSUE(0, 0);
  __syncthreads();                                     // drains vmcnt: buf0 ready

  for (int t = 0; t < 32; ++t){
    unsigned char* cur = smem[t & 1];
    if (t < 31) ISSUE((t + 1) * 64, (t + 1) & 1);      // async into other buffer
    long af[4][2], bf[2][2];
    #pragma unroll
    for (int ni = 0; ni < 4; ni++)
      #pragma unroll
      for (int kc = 0; kc < 2; kc++){
        int row = ni * 16 + l15;
        af[ni][kc] = *(const long*)(cur + row * 64 + ((kc * 32 + g * 8) ^ ((row & 3) << 4)));
      }
    #pragma unroll
    for (int oi = 0; oi < 2; oi++)
      #pragma unroll
      for (int kc = 0; kc < 2; kc++){
        int row = w * 32 + oi * 16 + l15;
        bf[oi][kc] = *(const long*)(cur + 4096 + row * 64 + ((kc * 32 + g * 8) ^ ((row & 3) << 4)));
      }
    #pragma unroll
    for (int ni = 0; ni < 4; ni++)
      #pragma unroll
      for (int oi = 0; oi < 2; oi++)
        #pragma unroll
        for (int kc = 0; kc < 2; kc++)
          acc[ni][oi] = __builtin_amdgcn_mfma_f32_16x16x32_fp8_fp8(af[ni][kc], bf[oi][kc], acc[ni][oi], 0, 0, 0);
    if (t < 31)
      __syncthreads();                                 // next buf ready; cur reads done
  }
  float inv[4][4];
  #pragma unroll
  for (int ni = 0; ni < 4; ni++)
    #pragma unroll
    for (int r = 0; r < 4; r++)
      inv[ni][r] = 1.0f / sbuf[(size_t)b * 2048 + n0 + ni * 16 + g * 4 + r];
  #pragma unroll
  for (int oi = 0; oi < 2; oi++){
    float cm = -1e30f;
    #pragma unroll
    for (int ni = 0; ni < 4; ni++)
      #pragma unroll
      for (int r = 0; r < 4; r++)
        cm = fmaxf(cm, acc[ni][oi][r] * inv[ni][r]);
    cm = fmaxf(cm, __shfl_xor(cm, 16));
    cm = fmaxf(cm, __shfl_xor(cm, 32));
    if (lane < 16)
      atomicMax(&tmaxe[b * 256 + oh * 128 + w * 32 + oi * 16 + lane], fenc(cm));
  }
}

// ---------------- K5: W_eff = P0 + P1*t + P2 (bf16); bias_eff; w0/w1 -> bf16 -----
__global__ __launch_bounds__(256) void k5_weff(const float* __restrict__ proj_w,
    const float* __restrict__ proj_b, const unsigned* __restrict__ tmaxe,
    const float* __restrict__ params, unsigned short* __restrict__ weff,
    float* __restrict__ beff, unsigned short* __restrict__ w0b,
    unsigned short* __restrict__ w1b){
  const int b = blockIdx.y, o = blockIdx.x;
  const int c = threadIdx.x;                  // 256
  float t = fdec(tmaxe[b * 256 + c]);
  float p0 = proj_w[o * 768 + c];
  float p1 = proj_w[o * 768 + 256 + c];
  float p2 = proj_w[o * 768 + 512 + c];
  weff[((size_t)b * 64 + o) * 256 + c] = f2bf(p0 + p1 * t + p2);
  float s = p0 * t;
  #pragma unroll
  for (int d = 1; d < 64; d <<= 1) s += __shfl_xor(s, d);
  __shared__ float sm[4];
  if ((c & 63) == 0) sm[c >> 6] = s;
  __syncthreads();
  if (c == 0) beff[b * 64 + o] = proj_b[o] - (sm[0] + sm[1] + sm[2] + sm[3]);
  if (c < 64)        w0b[((size_t)b * 64 + o) * 64 + c] = f2bf(params[b * 8385 + o * 64 + c]);
  else if (c < 128)  w1b[((size_t)b * 64 + o) * 64 + (c - 64)] = f2bf(params[b * 8385 + 4096 + o * 64 + (c - 64)]);
}

// ---------------- K6: fused scene pipeline (scene read exactly once) -------------
__global__ __launch_bounds__(512) void k6_main(const float* __restrict__ Sg,
    const unsigned short* __restrict__ weff, const float* __restrict__ beff,
    const unsigned short* __restrict__ w0b, const unsigned short* __restrict__ w1b,
    const float* __restrict__ params, float* __restrict__ out){
  const int b = blockIdx.y, nt = blockIdx.x;
  const int n0 = nt * 256;
  const int tid = threadIdx.x, lane = tid & 63, w = tid >> 6;
  const int l15 = lane & 15, g = lane >> 4;
  __shared__ __align__(16) unsigned char smem[65536];
  unsigned short* H0 = (unsigned short*)smem;            // [n][64] XOR-swizzled, 32 KB
  unsigned char*  Ub = smem + 32768;                     // Bs32 (16KB) then H1 (32KB)
  unsigned short* H1 = (unsigned short*)Ub;

  const float* Sb = Sg + (size_t)b * 256 * 16384;
  const unsigned short* We = weff + (size_t)b * 64 * 256;
  f32x4 a0[4][2];
  #pragma unroll
  for (int mi = 0; mi < 4; mi++)
    #pragma unroll
    for (int ni = 0; ni < 2; ni++) a0[mi][ni] = (f32x4){0.f,0.f,0.f,0.f};

  const int scc = tid & 31;                   // c row within k-tile
  const int snb = (tid >> 5) * 16;            // 16 n per thread
  const float* src0 = Sb + (size_t)scc * 16384 + n0 + snb;
  float4 v0 = ((const float4*)src0)[0];
  float4 v1 = ((const float4*)src0)[1];
  float4 v2 = ((const float4*)src0)[2];
  float4 v3 = ((const float4*)src0)[3];
  for (int k0 = 0; k0 < 256; k0 += 32){
    float vals[16] = {v0.x,v0.y,v0.z,v0.w, v1.x,v1.y,v1.z,v1.w,
                      v2.x,v2.y,v2.z,v2.w, v3.x,v3.y,v3.z,v3.w};
    #pragma unroll
    for (int j = 0; j < 16; j++){
      int n = snb + j;
      unsigned byteo = ((unsigned)(n * 64 + scc * 2)) ^ ((unsigned)((n >> 1) & 3) << 4);
      *(unsigned short*)(Ub + byteo) = f2bf(vals[j]);
    }
    if (k0 < 224){                            // prefetch next k-tile into regs
      const float* nsrc = Sb + (size_t)(k0 + 32 + scc) * 16384 + n0 + snb;
      v0 = ((const float4*)nsrc)[0];
      v1 = ((const float4*)nsrc)[1];
      v2 = ((const float4*)nsrc)[2];
      v3 = ((const float4*)nsrc)[3];
    }
    __syncthreads();
    short8 bf0[2];
    #pragma unroll
    for (int ni = 0; ni < 2; ni++){
      int n = w * 32 + ni * 16 + l15;
      bf0[ni] = *(const short8*)(Ub + (((unsigned)(n * 64 + g * 16)) ^ ((unsigned)((n >> 1) & 3) << 4)));
    }
    #pragma unroll
    for (int mi = 0; mi < 4; mi++){
      short8 af = *(const short8*)(We + (mi * 16 + l15) * 256 + k0 + g * 8);
      #pragma unroll
      for (int ni = 0; ni < 2; ni++)
        a0[mi][ni] = __builtin_amdgcn_mfma_f32_16x16x32_bf16(af, bf0[ni], a0[mi][ni], 0, 0, 0);
    }
    __syncthreads();
  }
  const float* be = beff + b * 64;
  #pragma unroll
  for (int mi = 0; mi < 4; mi++)
    #pragma unroll
    for (int ni = 0; ni < 2; ni++){
      int n = w * 32 + ni * 16 + l15;
      unsigned base = ((unsigned)(n * 128 + mi * 32 + g * 8)) ^ ((unsigned)((n & 7) << 4));
      unsigned short hh[4];
      #pragma unroll
      for (int r = 0; r < 4; r++){
        int o = mi * 16 + g * 4 + r;
        hh[r] = f2bf(fmaxf(a0[mi][ni][r] + be[o], 0.f));
      }
      *(unsigned*)((unsigned char*)H0 + base)     = (unsigned)hh[0] | ((unsigned)hh[1] << 16);
      *(unsigned*)((unsigned char*)H0 + base + 4) = (unsigned)hh[2] | ((unsigned)hh[3] << 16);
    }
  __syncthreads();
  f32x4 a1[4][2];
  #pragma unroll
  for (int mi = 0; mi < 4; mi++)
    #pragma unroll
    for (int ni = 0; ni < 2; ni++) a1[mi][ni] = (f32x4){0.f,0.f,0.f,0.f};
  const unsigned short* W0 = w0b + (size_t)b * 4096;
  #pragma unroll
  for (int ks = 0; ks < 2; ks++){
    short8 bfh[2];
    #pragma unroll
    for (int ni = 0; ni < 2; ni++){
      int n = w * 32 + ni * 16 + l15;
      unsigned off = ((unsigned)(n * 128 + ks * 64 + g * 16)) ^ ((unsigned)((n & 7) << 4));
      bfh[ni] = *(const short8*)((unsigned char*)H0 + off);
    }
    #pragma unroll
    for (int mi = 0; mi < 4; mi++){
      short8 af = *(const short8*)(W0 + (mi * 16 + l15) * 64 + ks * 32 + g * 8);
      #pragma unroll
      for (int ni = 0; ni < 2; ni++)
        a1[mi][ni] = __builtin_amdgcn_mfma_f32_16x16x32_bf16(af, bfh[ni], a1[mi][ni], 0, 0, 0);
    }
  }
  const float* pp = params + (size_t)b * 8385;
  const float* b0p = pp + 8256;
  #pragma unroll
  for (int mi = 0; mi < 4; mi++)
    #pragma unroll
    for (int ni = 0; ni < 2; ni++){
      int n = w * 32 + ni * 16 + l15;
      unsigned base = ((unsigned)(n * 128 + mi * 32 + g * 8)) ^ ((unsigned)((n & 7) << 4));
      unsigned short hh[4];
      #pragma unroll
      for (int r = 0; r < 4; r++){
        int o = mi * 16 + g * 4 + r;
        hh[r] = f2bf(fmaxf(a1[mi][ni][r] + b0p[o], 0.f));
      }
      *(unsigned*)((unsigned char*)H1 + base)     = (unsigned)hh[0] | ((unsigned)hh[1] << 16);
      *(unsigned*)((unsigned char*)H1 + base + 4) = (unsigned)hh[2] | ((unsigned)hh[3] << 16);
    }
  __syncthreads();
  f32x4 a2[4][2];
  #pragma unroll
  for (int mi = 0; mi < 4; mi++)
    #pragma unroll
    for (int ni = 0; ni < 2; ni++) a2[mi][ni] = (f32x4){0.f,0.f,0.f,0.f};
  const unsigned short* W1 = w1b + (size_t)b * 4096;
  #pragma unroll
  for (int ks = 0; ks < 2; ks++){
    short8 bfh[2];
    #pragma unroll
    for (int ni = 0; ni < 2; ni++){
      int n = w * 32 + ni * 16 + l15;
      unsigned off = ((unsigned)(n * 128 + ks * 64 + g * 16)) ^ ((unsigned)((n & 7) << 4));
      bfh[ni] = *(const short8*)((unsigned char*)H1 + off);
    }
    #pragma unroll
    for (int mi = 0; mi < 4; mi++){
      short8 af = *(const short8*)(W1 + (mi * 16 + l15) * 64 + ks * 32 + g * 8);
      #pragma unroll
      for (int ni = 0; ni < 2; ni++)
        a2[mi][ni] = __builtin_amdgcn_mfma_f32_16x16x32_bf16(af, bfh[ni], a2[mi][ni], 0, 0, 0);
    }
  }
  const float* b1p = pp + 8320;
  const float* w2p = pp + 8192;
  float b2v = pp[8384];
  #pragma unroll
  for (int ni = 0; ni < 2; ni++){
    float t = 0.f;
    #pragma unroll
    for (int mi = 0; mi < 4; mi++)
      #pragma unroll
      for (int r = 0; r < 4; r++){
        int o = mi * 16 + g * 4 + r;
        t += w2p[o] * fmaxf(a2[mi][ni][r] + b1p[o], 0.f);
      }
    t += __shfl_xor(t, 16);
    t += __shfl_xor(t, 32);
    if (lane < 16)
      out[(size_t)b * 16384 + n0 + w * 32 + ni * 16 + l15] = t + b2v;
  }
}

extern "C" void kernel_launch(void* const* d_in, const int* in_sizes, int n_in,
                              void* d_out, int out_size, void* d_ws, size_t ws_size,
                              hipStream_t stream){
  const float* scene = (const float*)d_in[0];
  const float* tmpl  = (const float*)d_in[1];
  const float* qw    = (const float*)d_in[2];
  const float* kw    = (const float*)d_in[3];
  const float* vw    = (const float*)d_in[4];
  const float* pw    = (const float*)d_in[5];
  const float* pb    = (const float*)d_in[6];
  const float* cw    = (const float*)d_in[7];
  const float* cb    = (const float*)d_in[8];
  float* out = (float*)d_out;
  char* ws = (char*)d_ws;

  unsigned short* Q      = (unsigned short*)(ws + 0);                    // 2 MB
  unsigned short* K      = (unsigned short*)(ws + (2u << 20));           // 2 MB
  unsigned char*  V8     = (unsigned char*)(ws + (4u << 20));            // 4 MB
  unsigned*       pooledEnc = (unsigned*)(ws + (12u << 20));             // 8 KB
  unsigned*       tmaxe  = (unsigned*)(ws + (12u << 20) + 8192);         // 8 KB
  float*          params = (float*)(ws + (12u << 20) + 16384);           // 268 KB
  unsigned short* w0b    = (unsigned short*)(ws + (13u << 20));          // 64 KB
  unsigned short* w1b    = (unsigned short*)(ws + (13u << 20) + 65536);  // 64 KB
  unsigned short* weff   = (unsigned short*)(ws + (13u << 20) + 131072); // 256 KB
  float*          beff   = (float*)(ws + (13u << 20) + 131072 + 262144); // 2 KB
  float*          sbuf   = (float*)(ws + (14u << 20));                   // 64 KB
  unsigned short* Wbf    = (unsigned short*)(ws + (14u << 20) + 131072); // 192 KB
  unsigned char*  P8buf  = (unsigned char*)(ws + (16u << 20));           // up to 33.5 MB
  unsigned short* Tt     = (unsigned short*)P8buf;  // 8 MB; dead before kA writes

  const size_t pPerBatch = (size_t)2048 * 2048;     // 4 MB fp8 per batch
  size_t avail = ws_size > (16u << 20) ? ws_size - (16u << 20) : 0;
  int nb = 8, bshift = 3;
  while (nb > 1 && (size_t)nb * pPerBatch > avail){ nb >>= 1; bshift--; }

  k0w<<<dim3(96), dim3(256), 0, stream>>>(qw, kw, vw, Wbf, tmaxe, pooledEnc);
  k0_tt<<<dim3(8, 16, 8), dim3(256), 0, stream>>>(tmpl, Tt, pooledEnc);
  k23_qkv_params<<<dim3(512 + 2097), dim3(256), 0, stream>>>(Wbf, Tt, Q, K, V8,
                                                             pooledEnc, cw, cb, params);
  for (int b0 = 0; b0 < 8; b0 += nb){
    kA_scores<<<dim3(64 * nb), dim3(512), 0, stream>>>(Q, K, P8buf, sbuf, b0, bshift);
    kB_pv<<<dim3(64 * nb), dim3(256), 0, stream>>>(P8buf, V8, sbuf, tmaxe, b0, bshift);
  }
  k5_weff<<<dim3(64, 8), dim3(256), 0, stream>>>(pw, pb, tmaxe, params, weff, beff, w0b, w1b);
  k6_main<<<dim3(64, 8), dim3(512), 0, stream>>>(scene, weff, beff, w0b, w1b, params, out);
}

// Round 15
// 130.737 us; speedup vs baseline: 1.3448x; 1.0717x over previous
//
#include <hip/hip_runtime.h>
#include <hip/hip_fp8.h>

// DynamicConvolution fused pipeline for MI355X (gfx950).
// R15 (base = R14, 140.1): kB switched to MX-scaled fp8 MFMA
// (mfma_scale_f32_16x16x128_f8f6f4, scale=1.0) -> 2x matrix rate, 4x fewer
// MFMA instructions; m-chunks 128, LDS dbuf 2x24KB, 32B-granule swizzle
// (row&3)<<5 (frag reads stay 32B-aligned). k0w launch deleted: weights fold
// into k0_tt's grid; tmaxe/pooledEnc init via one hipMemsetAsync (floor 0 is
// valid for the monotone float encoding).
// Stages: memset -> k0_tt(+weights) -> k23 qkv+params -> kA exp(QK^T) ->
//         kB PV+tmax -> k5 W_eff -> k6 fused scene MLP.

typedef __attribute__((ext_vector_type(8))) short short8;
typedef __attribute__((ext_vector_type(4))) short short4v;
typedef __attribute__((ext_vector_type(4))) float f32x4;
typedef __attribute__((ext_vector_type(8))) int int8v;

__device__ __forceinline__ unsigned short f2bf(float f){
  unsigned u = __float_as_uint(f);
  u += 0x7FFFu + ((u >> 16) & 1u);           // round-to-nearest-even
  return (unsigned short)(u >> 16);
}
__device__ __forceinline__ unsigned char f2e4m3(float f){
  return __hip_fp8_e4m3(f).__x;              // OCP e4m3 (gfx950 HW format)
}
// monotone float<->uint for atomicMax on floats (incl. negatives)
__device__ __forceinline__ unsigned fenc(float f){
  unsigned u = __float_as_uint(f);
  return (u & 0x80000000u) ? ~u : (u | 0x80000000u);
}
__device__ __forceinline__ float fdec(unsigned k){
  unsigned u = (k & 0x80000000u) ? (k & 0x7FFFFFFFu) : ~k;
  return __uint_as_float(u);
}

// ---------------- k0_tt: Tt[b][n][c] = bf16(T[b][c][n]) + pooled max;
//                  wg>=1024: Wbf[384][256] bf16 (q*0.125 folded) ----------------
__global__ __launch_bounds__(256) void k0_tt(const float* __restrict__ T,
    unsigned short* __restrict__ Tt, unsigned* __restrict__ pooledEnc,
    const float* __restrict__ qw, const float* __restrict__ kw,
    const float* __restrict__ vw, unsigned short* __restrict__ Wbf){
  const int wg = blockIdx.x;
  const int tid = threadIdx.x;
  if (wg >= 1024){                            // weight conversion (96 WGs)
    const int e = ((wg - 1024) * 256 + tid) * 4;
    const int row = e >> 8, c = e & 255;
    const float* src;
    float scl = 1.0f;
    if (row < 64){ src = qw + row * 256 + c; scl = 0.125f; }
    else if (row < 128){ src = kw + (row - 64) * 256 + c; }
    else { src = vw + (row - 128) * 256 + c; }
    float4 v = *(const float4*)src;
    short4v o;
    o[0] = (short)f2bf(v.x * scl); o[1] = (short)f2bf(v.y * scl);
    o[2] = (short)f2bf(v.z * scl); o[3] = (short)f2bf(v.w * scl);
    *(short4v*)(Wbf + e) = o;
    return;
  }
  const int b = wg & 7, nt = (wg >> 3) & 15, ct = wg >> 7;
  const int n0 = nt * 128, c0 = ct * 32;
  __shared__ float Ls[32][129];
  const int cr = tid >> 3, nq = tid & 7;      // 32 c-rows x 8 n-chunks(16 f32)
  const float* src = T + ((size_t)b * 256 + c0 + cr) * 2048 + n0 + nq * 16;
  float4 v0 = ((const float4*)src)[0];
  float4 v1 = ((const float4*)src)[1];
  float4 v2 = ((const float4*)src)[2];
  float4 v3 = ((const float4*)src)[3];
  float mx = fmaxf(fmaxf(fmaxf(v0.x, v0.y), fmaxf(v0.z, v0.w)),
                   fmaxf(fmaxf(v1.x, v1.y), fmaxf(v1.z, v1.w)));
  mx = fmaxf(mx, fmaxf(fmaxf(fmaxf(v2.x, v2.y), fmaxf(v2.z, v2.w)),
                       fmaxf(fmaxf(v3.x, v3.y), fmaxf(v3.z, v3.w))));
  mx = fmaxf(mx, __shfl_xor(mx, 1));
  mx = fmaxf(mx, __shfl_xor(mx, 2));
  mx = fmaxf(mx, __shfl_xor(mx, 4));
  if (nq == 0) atomicMax(&pooledEnc[b * 256 + c0 + cr], fenc(mx));
  float* lr = &Ls[cr][nq * 16];
  *(float4*)lr = v0; *(float4*)(lr + 4) = v1;
  *(float4*)(lr + 8) = v2; *(float4*)(lr + 12) = v3;
  __syncthreads();
  const int nr = tid >> 1, ch = tid & 1;      // 128 n-rows x 2 c-halves(16)
  unsigned short ob[16];
  #pragma unroll
  for (int j = 0; j < 16; j++) ob[j] = f2bf(Ls[ch * 16 + j][nr]);
  unsigned short* dst = Tt + ((size_t)b * 2048 + n0 + nr) * 256 + c0 + ch * 16;
  *(short8*)dst = *(short8*)&ob[0];
  *(short8*)(dst + 8) = *(short8*)&ob[8];
}

// ---------------- k23: fused k2 (QKV gemm, wg<512) + k3 (params gemv) ------------
// V output fp8 e4m3: vt8[b][o][n] (1 B/elem), packed u32 stores.
__global__ __launch_bounds__(256) void k23_qkv_params(
    const unsigned short* __restrict__ Wbf, const unsigned short* __restrict__ Tt,
    unsigned short* __restrict__ qo, unsigned short* __restrict__ ko,
    unsigned char* __restrict__ vt8,
    const unsigned* __restrict__ pooledEnc, const float* __restrict__ cw,
    const float* __restrict__ cb, float* __restrict__ params){
  const int wg = blockIdx.x;
  const int tid = threadIdx.x, lane = tid & 63, w = tid >> 6;
  if (wg >= 512){
    __shared__ float P[8 * 256];
    for (int i = tid; i < 2048; i += 256) P[i] = fdec(pooledEnc[i]);
    __syncthreads();
    const int r = (wg - 512) * 4 + w;
    if (r >= 8385) return;
    float4 c4 = ((const float4*)(cw + (size_t)r * 256))[lane];
    float bias = cb[r];
    #pragma unroll
    for (int b = 0; b < 8; b++){
      const float* pbp = P + b * 256 + lane * 4;
      float s = c4.x * pbp[0] + c4.y * pbp[1] + c4.z * pbp[2] + c4.w * pbp[3];
      #pragma unroll
      for (int d = 1; d < 64; d <<= 1) s += __shfl_xor(s, d);
      if (lane == 0) params[b * 8385 + r] = s + bias;
    }
    return;
  }
  const int b = wg & 7, nt = wg >> 3;
  const int n0 = nt * 32;
  const int l15 = lane & 15, g = lane >> 4;
  const unsigned short* Tb = Tt + (size_t)b * 2048 * 256;

  f32x4 aqk[2][2], av[4][2];
  #pragma unroll
  for (int i = 0; i < 2; i++)
    #pragma unroll
    for (int nf = 0; nf < 2; nf++) aqk[i][nf] = (f32x4){0.f,0.f,0.f,0.f};
  #pragma unroll
  for (int j = 0; j < 4; j++)
    #pragma unroll
    for (int nf = 0; nf < 2; nf++) av[j][nf] = (f32x4){0.f,0.f,0.f,0.f};

  #pragma unroll 2
  for (int kc = 0; kc < 8; kc++){
    short8 bfr[2];
    #pragma unroll
    for (int nf = 0; nf < 2; nf++)
      bfr[nf] = *(const short8*)(Tb + (size_t)(n0 + nf * 16 + l15) * 256 + kc * 32 + g * 8);
    short8 aq[2];
    #pragma unroll
    for (int i = 0; i < 2; i++)
      aq[i] = *(const short8*)(Wbf + (size_t)((2 * w + i) * 16 + l15) * 256 + kc * 32 + g * 8);
    short8 afv[4];
    #pragma unroll
    for (int j = 0; j < 4; j++)
      afv[j] = *(const short8*)(Wbf + (size_t)(128 + (4 * w + j) * 16 + l15) * 256 + kc * 32 + g * 8);
    #pragma unroll
    for (int i = 0; i < 2; i++)
      #pragma unroll
      for (int nf = 0; nf < 2; nf++)
        aqk[i][nf] = __builtin_amdgcn_mfma_f32_16x16x32_bf16(aq[i], bfr[nf], aqk[i][nf], 0, 0, 0);
    #pragma unroll
    for (int j = 0; j < 4; j++)
      #pragma unroll
      for (int nf = 0; nf < 2; nf++)
        av[j][nf] = __builtin_amdgcn_mfma_f32_16x16x32_bf16(bfr[nf], afv[j], av[j][nf], 0, 0, 0);
  }
  unsigned short* qk = (w < 2) ? qo : ko;
  #pragma unroll
  for (int i = 0; i < 2; i++)
    #pragma unroll
    for (int nf = 0; nf < 2; nf++){
      int n = n0 + nf * 16 + l15;
      int cbase = (w & 1) * 32 + i * 16 + g * 4;
      short4v pk;
      #pragma unroll
      for (int r = 0; r < 4; r++) pk[r] = (short)f2bf(aqk[i][nf][r]);
      *(short4v*)(qk + ((size_t)b * 2048 + n) * 64 + cbase) = pk;
    }
  #pragma unroll
  for (int j = 0; j < 4; j++)
    #pragma unroll
    for (int nf = 0; nf < 2; nf++){
      int o = (4 * w + j) * 16 + l15;
      int nb2 = n0 + nf * 16 + g * 4;
      unsigned pv8 = 0;
      #pragma unroll
      for (int r = 0; r < 4; r++)
        pv8 |= (unsigned)f2e4m3(av[j][nf][r]) << (8 * r);
      *(unsigned*)(vt8 + ((size_t)b * 256 + o) * 2048 + nb2) = pv8;
    }
}

// ---------------- kA v5: swapped QK -> P fp8 row-major [q][2048] -----------------
__global__ __launch_bounds__(512, 4) void kA_scores(
    const unsigned short* __restrict__ Qg, const unsigned short* __restrict__ Kg,
    unsigned char* __restrict__ Pg, float* __restrict__ sbuf,
    int b0, int bshift){
  const int wg = blockIdx.x;
  const int bmask = (1 << bshift) - 1;
  const int b = b0 + (wg & bmask);
  const int q0 = (wg >> bshift) * 32;
  const int tid = threadIdx.x, lane = tid & 63, w = tid >> 6;
  const int l15 = lane & 15, g = lane >> 4;
  __shared__ float wsum[32][8];
  const unsigned short* Qb = Qg + (size_t)b * 2048 * 64;
  const unsigned short* Kb = Kg + (size_t)b * 2048 * 64;
  unsigned char* Pb = Pg + (size_t)(wg & bmask) * 2048 * 2048;

  short8 qf[2][2];
  #pragma unroll
  for (int qi = 0; qi < 2; qi++)
    #pragma unroll
    for (int kc = 0; kc < 2; kc++)
      qf[qi][kc] = *(const short8*)(Qb + (size_t)(q0 + qi * 16 + l15) * 64 + kc * 32 + g * 8);

  float ps[2] = {0.f, 0.f};                   // per-lane partial for q = qi*16+l15

  const int wm0 = w * 256;
  #pragma unroll
  for (int mt = 0; mt < 4; ++mt){
    const int mb = wm0 + mt * 64;
    short8 kf[4][2];
    #pragma unroll
    for (int mi = 0; mi < 4; mi++)
      #pragma unroll
      for (int kc = 0; kc < 2; kc++)
        kf[mi][kc] = *(const short8*)(Kb + (size_t)(mb + mi * 16 + l15) * 64 + kc * 32 + g * 8);
    #pragma unroll
    for (int qi = 0; qi < 2; qi++){
      f32x4 sa[4];
      #pragma unroll
      for (int mi = 0; mi < 4; mi++) sa[mi] = (f32x4){0.f,0.f,0.f,0.f};
      #pragma unroll
      for (int mi = 0; mi < 4; mi++)
        #pragma unroll
        for (int kc = 0; kc < 2; kc++)
          sa[mi] = __builtin_amdgcn_mfma_f32_16x16x32_bf16(kf[mi][kc], qf[qi][kc], sa[mi], 0, 0, 0);
      #pragma unroll
      for (int mi = 0; mi < 4; mi++){
        unsigned pk8 = 0;
        #pragma unroll
        for (int r = 0; r < 4; r++){
          float p = __expf(sa[mi][r]);        // sa[mi][r] = S[m=mb+mi*16+g*4+r][q]
          ps[qi] += p;
          pk8 |= (unsigned)f2e4m3(p) << (8 * r);
        }
        *(unsigned*)(Pb + (size_t)(q0 + qi * 16 + l15) * 2048 + mb + mi * 16 + g * 4) = pk8;
      }
    }
  }
  #pragma unroll
  for (int qi = 0; qi < 2; qi++){
    float t = ps[qi];
    t += __shfl_xor(t, 16);
    t += __shfl_xor(t, 32);                   // sum over the 4 g-groups
    if (lane < 16) wsum[qi * 16 + l15][w] = t;
  }
  __syncthreads();
  if (tid < 32){
    float t = 0.f;
    #pragma unroll
    for (int i = 0; i < 8; i++) t += wsum[tid][i];
    sbuf[(size_t)b * 2048 + q0 + tid] = t;
  }
}

// ---------------- kB v7: O = P8@V8^T via MX-scaled fp8 MFMA (K=128) --------------
// grid 64*nb (b; oh = o-half; nt -> 64 n-rows). m-chunks of 128. LDS dbuf
// 2x24KB (P 8KB + V 16KB fp8, [row][128B], 32B-granule swizzle (row&3)<<5).
// 6 x global_load_lds(16B)/lane, source pre-swizzled. Frags int8v (32B);
// 8 x mfma_scale_f32_16x16x128_f8f6f4 per chunk (scale=1.0). 3 WG/CU.
__global__ __launch_bounds__(256, 3) void kB_pv(
    const unsigned char* __restrict__ Pg, const unsigned char* __restrict__ Vt,
    const float* __restrict__ sbuf, unsigned* __restrict__ tmaxe,
    int b0, int bshift){
  const int wg = blockIdx.x;
  const int bmask = (1 << bshift) - 1;
  const int b = b0 + (wg & bmask);
  const int rest = wg >> bshift;
  const int oh = rest & 1;
  const int n0 = (rest >> 1) * 64;
  const int tid = threadIdx.x, lane = tid & 63, w = tid >> 6;
  const int l15 = lane & 15, g = lane >> 4;
  __shared__ __align__(32) unsigned char smem[2][24576];  // dbuf: Pl 8KB | Vl 16KB

  const unsigned char* Pb = Pg + (size_t)(wg & bmask) * 2048 * 2048;
  const unsigned char* Vb = Vt + ((size_t)b * 256 + oh * 128) * 2048;

  f32x4 acc[4][2];
  #pragma unroll
  for (int ni = 0; ni < 4; ni++)
    #pragma unroll
    for (int oi = 0; oi < 2; oi++) acc[ni][oi] = (f32x4){0.f,0.f,0.f,0.f};

  // per-lane pre-swizzled sources: d = k*4096 + w*1024 + lane*16
  const unsigned char* psrc[6];
  {
    #pragma unroll
    for (int k = 0; k < 6; k++){
      int d = k * 4096 + w * 1024 + lane * 16;
      if (k < 2){                                        // P: 64 rows x 128B
        int row = d >> 7;
        int colB = (d & 127) ^ ((row & 3) << 5);
        psrc[k] = Pb + (size_t)(n0 + row) * 2048 + colB;
      } else {                                           // V-half: 128 rows x 128B
        int dv = d - 8192;
        int row = dv >> 7;
        int colB = (dv & 127) ^ ((row & 3) << 5);
        psrc[k] = Vb + (size_t)row * 2048 + colB;
      }
    }
  }
  auto ISSUE = [&](int m0, int bufIdx){
    #pragma unroll
    for (int k = 0; k < 6; k++){
      unsigned char* dst = &smem[bufIdx][k * 4096 + w * 1024];  // wave-uniform
      __builtin_amdgcn_global_load_lds(
          (const __attribute__((address_space(1))) void*)(psrc[k] + m0),
          (__attribute__((address_space(3))) void*)dst, 16, 0, 0);
    }
  };

  ISSUE(0, 0);
  __syncthreads();                                     // drains vmcnt: buf0 ready

  const int SC = 0x7F7F7F7F;                           // E8M0 1.0 per block
  for (int t = 0; t < 16; ++t){
    unsigned char* cur = smem[t & 1];
    if (t < 15) ISSUE((t + 1) * 128, (t + 1) & 1);     // async into other buffer
    int8v af[4], bf[2];
    #pragma unroll
    for (int ni = 0; ni < 4; ni++){
      int row = ni * 16 + l15;
      af[ni] = *(const int8v*)(cur + row * 128 + ((g * 32) ^ ((row & 3) << 5)));
    }
    #pragma unroll
    for (int oi = 0; oi < 2; oi++){
      int row = w * 32 + oi * 16 + l15;
      bf[oi] = *(const int8v*)(cur + 8192 + row * 128 + ((g * 32) ^ ((row & 3) << 5)));
    }
    #pragma unroll
    for (int ni = 0; ni < 4; ni++)
      #pragma unroll
      for (int oi = 0; oi < 2; oi++)
        acc[ni][oi] = __builtin_amdgcn_mfma_scale_f32_16x16x128_f8f6f4(
            af[ni], bf[oi], acc[ni][oi], 0, 0, 0, SC, 0, SC);
    if (t < 15)
      __syncthreads();                                 // next buf ready; cur reads done
  }
  float inv[4][4];
  #pragma unroll
  for (int ni = 0; ni < 4; ni++)
    #pragma unroll
    for (int r = 0; r < 4; r++)
      inv[ni][r] = 1.0f / sbuf[(size_t)b * 2048 + n0 + ni * 16 + g * 4 + r];
  #pragma unroll
  for (int oi = 0; oi < 2; oi++){
    float cm = -1e30f;
    #pragma unroll
    for (int ni = 0; ni < 4; ni++)
      #pragma unroll
      for (int r = 0; r < 4; r++)
        cm = fmaxf(cm, acc[ni][oi][r] * inv[ni][r]);
    cm = fmaxf(cm, __shfl_xor(cm, 16));
    cm = fmaxf(cm, __shfl_xor(cm, 32));
    if (lane < 16)
      atomicMax(&tmaxe[b * 256 + oh * 128 + w * 32 + oi * 16 + lane], fenc(cm));
  }
}

// ---------------- K5: W_eff = P0 + P1*t + P2 (bf16); bias_eff; w0/w1 -> bf16 -----
__global__ __launch_bounds__(256) void k5_weff(const float* __restrict__ proj_w,
    const float* __restrict__ proj_b, const unsigned* __restrict__ tmaxe,
    const float* __restrict__ params, unsigned short* __restrict__ weff,
    float* __restrict__ beff, unsigned short* __restrict__ w0b,
    unsigned short* __restrict__ w1b){
  const int b = blockIdx.y, o = blockIdx.x;
  const int c = threadIdx.x;                  // 256
  float t = fdec(tmaxe[b * 256 + c]);
  float p0 = proj_w[o * 768 + c];
  float p1 = proj_w[o * 768 + 256 + c];
  float p2 = proj_w[o * 768 + 512 + c];
  weff[((size_t)b * 64 + o) * 256 + c] = f2bf(p0 + p1 * t + p2);
  float s = p0 * t;
  #pragma unroll
  for (int d = 1; d < 64; d <<= 1) s += __shfl_xor(s, d);
  __shared__ float sm[4];
  if ((c & 63) == 0) sm[c >> 6] = s;
  __syncthreads();
  if (c == 0) beff[b * 64 + o] = proj_b[o] - (sm[0] + sm[1] + sm[2] + sm[3]);
  if (c < 64)        w0b[((size_t)b * 64 + o) * 64 + c] = f2bf(params[b * 8385 + o * 64 + c]);
  else if (c < 128)  w1b[((size_t)b * 64 + o) * 64 + (c - 64)] = f2bf(params[b * 8385 + 4096 + o * 64 + (c - 64)]);
}

// ---------------- K6: fused scene pipeline (scene read exactly once) -------------
__global__ __launch_bounds__(512) void k6_main(const float* __restrict__ Sg,
    const unsigned short* __restrict__ weff, const float* __restrict__ beff,
    const unsigned short* __restrict__ w0b, const unsigned short* __restrict__ w1b,
    const float* __restrict__ params, float* __restrict__ out){
  const int b = blockIdx.y, nt = blockIdx.x;
  const int n0 = nt * 256;
  const int tid = threadIdx.x, lane = tid & 63, w = tid >> 6;
  const int l15 = lane & 15, g = lane >> 4;
  __shared__ __align__(16) unsigned char smem[65536];
  unsigned short* H0 = (unsigned short*)smem;            // [n][64] XOR-swizzled, 32 KB
  unsigned char*  Ub = smem + 32768;                     // Bs32 (16KB) then H1 (32KB)
  unsigned short* H1 = (unsigned short*)Ub;

  const float* Sb = Sg + (size_t)b * 256 * 16384;
  const unsigned short* We = weff + (size_t)b * 64 * 256;
  f32x4 a0[4][2];
  #pragma unroll
  for (int mi = 0; mi < 4; mi++)
    #pragma unroll
    for (int ni = 0; ni < 2; ni++) a0[mi][ni] = (f32x4){0.f,0.f,0.f,0.f};

  const int scc = tid & 31;                   // c row within k-tile
  const int snb = (tid >> 5) * 16;            // 16 n per thread
  const float* src0 = Sb + (size_t)scc * 16384 + n0 + snb;
  float4 v0 = ((const float4*)src0)[0];
  float4 v1 = ((const float4*)src0)[1];
  float4 v2 = ((const float4*)src0)[2];
  float4 v3 = ((const float4*)src0)[3];
  for (int k0 = 0; k0 < 256; k0 += 32){
    float vals[16] = {v0.x,v0.y,v0.z,v0.w, v1.x,v1.y,v1.z,v1.w,
                      v2.x,v2.y,v2.z,v2.w, v3.x,v3.y,v3.z,v3.w};
    #pragma unroll
    for (int j = 0; j < 16; j++){
      int n = snb + j;
      unsigned byteo = ((unsigned)(n * 64 + scc * 2)) ^ ((unsigned)((n >> 1) & 3) << 4);
      *(unsigned short*)(Ub + byteo) = f2bf(vals[j]);
    }
    if (k0 < 224){                            // prefetch next k-tile into regs
      const float* nsrc = Sb + (size_t)(k0 + 32 + scc) * 16384 + n0 + snb;
      v0 = ((const float4*)nsrc)[0];
      v1 = ((const float4*)nsrc)[1];
      v2 = ((const float4*)nsrc)[2];
      v3 = ((const float4*)nsrc)[3];
    }
    __syncthreads();
    short8 bf0[2];
    #pragma unroll
    for (int ni = 0; ni < 2; ni++){
      int n = w * 32 + ni * 16 + l15;
      bf0[ni] = *(const short8*)(Ub + (((unsigned)(n * 64 + g * 16)) ^ ((unsigned)((n >> 1) & 3) << 4)));
    }
    #pragma unroll
    for (int mi = 0; mi < 4; mi++){
      short8 af = *(const short8*)(We + (mi * 16 + l15) * 256 + k0 + g * 8);
      #pragma unroll
      for (int ni = 0; ni < 2; ni++)
        a0[mi][ni] = __builtin_amdgcn_mfma_f32_16x16x32_bf16(af, bf0[ni], a0[mi][ni], 0, 0, 0);
    }
    __syncthreads();
  }
  const float* be = beff + b * 64;
  #pragma unroll
  for (int mi = 0; mi < 4; mi++)
    #pragma unroll
    for (int ni = 0; ni < 2; ni++){
      int n = w * 32 + ni * 16 + l15;
      unsigned base = ((unsigned)(n * 128 + mi * 32 + g * 8)) ^ ((unsigned)((n & 7) << 4));
      unsigned short hh[4];
      #pragma unroll
      for (int r = 0; r < 4; r++){
        int o = mi * 16 + g * 4 + r;
        hh[r] = f2bf(fmaxf(a0[mi][ni][r] + be[o], 0.f));
      }
      *(unsigned*)((unsigned char*)H0 + base)     = (unsigned)hh[0] | ((unsigned)hh[1] << 16);
      *(unsigned*)((unsigned char*)H0 + base + 4) = (unsigned)hh[2] | ((unsigned)hh[3] << 16);
    }
  __syncthreads();
  f32x4 a1[4][2];
  #pragma unroll
  for (int mi = 0; mi < 4; mi++)
    #pragma unroll
    for (int ni = 0; ni < 2; ni++) a1[mi][ni] = (f32x4){0.f,0.f,0.f,0.f};
  const unsigned short* W0 = w0b + (size_t)b * 4096;
  #pragma unroll
  for (int ks = 0; ks < 2; ks++){
    short8 bfh[2];
    #pragma unroll
    for (int ni = 0; ni < 2; ni++){
      int n = w * 32 + ni * 16 + l15;
      unsigned off = ((unsigned)(n * 128 + ks * 64 + g * 16)) ^ ((unsigned)((n & 7) << 4));
      bfh[ni] = *(const short8*)((unsigned char*)H0 + off);
    }
    #pragma unroll
    for (int mi = 0; mi < 4; mi++){
      short8 af = *(const short8*)(W0 + (mi * 16 + l15) * 64 + ks * 32 + g * 8);
      #pragma unroll
      for (int ni = 0; ni < 2; ni++)
        a1[mi][ni] = __builtin_amdgcn_mfma_f32_16x16x32_bf16(af, bfh[ni], a1[mi][ni], 0, 0, 0);
    }
  }
  const float* pp = params + (size_t)b * 8385;
  const float* b0p = pp + 8256;
  #pragma unroll
  for (int mi = 0; mi < 4; mi++)
    #pragma unroll
    for (int ni = 0; ni < 2; ni++){
      int n = w * 32 + ni * 16 + l15;
      unsigned base = ((unsigned)(n * 128 + mi * 32 + g * 8)) ^ ((unsigned)((n & 7) << 4));
      unsigned short hh[4];
      #pragma unroll
      for (int r = 0; r < 4; r++){
        int o = mi * 16 + g * 4 + r;
        hh[r] = f2bf(fmaxf(a1[mi][ni][r] + b0p[o], 0.f));
      }
      *(unsigned*)((unsigned char*)H1 + base)     = (unsigned)hh[0] | ((unsigned)hh[1] << 16);
      *(unsigned*)((unsigned char*)H1 + base + 4) = (unsigned)hh[2] | ((unsigned)hh[3] << 16);
    }
  __syncthreads();
  f32x4 a2[4][2];
  #pragma unroll
  for (int mi = 0; mi < 4; mi++)
    #pragma unroll
    for (int ni = 0; ni < 2; ni++) a2[mi][ni] = (f32x4){0.f,0.f,0.f,0.f};
  const unsigned short* W1 = w1b + (size_t)b * 4096;
  #pragma unroll
  for (int ks = 0; ks < 2; ks++){
    short8 bfh[2];
    #pragma unroll
    for (int ni = 0; ni < 2; ni++){
      int n = w * 32 + ni * 16 + l15;
      unsigned off = ((unsigned)(n * 128 + ks * 64 + g * 16)) ^ ((unsigned)((n & 7) << 4));
      bfh[ni] = *(const short8*)((unsigned char*)H1 + off);
    }
    #pragma unroll
    for (int mi = 0; mi < 4; mi++){
      short8 af = *(const short8*)(W1 + (mi * 16 + l15) * 64 + ks * 32 + g * 8);
      #pragma unroll
      for (int ni = 0; ni < 2; ni++)
        a2[mi][ni] = __builtin_amdgcn_mfma_f32_16x16x32_bf16(af, bfh[ni], a2[mi][ni], 0, 0, 0);
    }
  }
  const float* b1p = pp + 8320;
  const float* w2p = pp + 8192;
  float b2v = pp[8384];
  #pragma unroll
  for (int ni = 0; ni < 2; ni++){
    float t = 0.f;
    #pragma unroll
    for (int mi = 0; mi < 4; mi++)
      #pragma unroll
      for (int r = 0; r < 4; r++){
        int o = mi * 16 + g * 4 + r;
        t += w2p[o] * fmaxf(a2[mi][ni][r] + b1p[o], 0.f);
      }
    t += __shfl_xor(t, 16);
    t += __shfl_xor(t, 32);
    if (lane < 16)
      out[(size_t)b * 16384 + n0 + w * 32 + ni * 16 + l15] = t + b2v;
  }
}

extern "C" void kernel_launch(void* const* d_in, const int* in_sizes, int n_in,
                              void* d_out, int out_size, void* d_ws, size_t ws_size,
                              hipStream_t stream){
  const float* scene = (const float*)d_in[0];
  const float* tmpl  = (const float*)d_in[1];
  const float* qw    = (const float*)d_in[2];
  const float* kw    = (const float*)d_in[3];
  const float* vw    = (const float*)d_in[4];
  const float* pw    = (const float*)d_in[5];
  const float* pb    = (const float*)d_in[6];
  const float* cw    = (const float*)d_in[7];
  const float* cb    = (const float*)d_in[8];
  float* out = (float*)d_out;
  char* ws = (char*)d_ws;

  unsigned short* Q      = (unsigned short*)(ws + 0);                    // 2 MB
  unsigned short* K      = (unsigned short*)(ws + (2u << 20));           // 2 MB
  unsigned char*  V8     = (unsigned char*)(ws + (4u << 20));            // 4 MB
  unsigned*       pooledEnc = (unsigned*)(ws + (12u << 20));             // 8 KB
  unsigned*       tmaxe  = (unsigned*)(ws + (12u << 20) + 8192);         // 8 KB
  float*          params = (float*)(ws + (12u << 20) + 16384);           // 268 KB
  unsigned short* w0b    = (unsigned short*)(ws + (13u << 20));          // 64 KB
  unsigned short* w1b    = (unsigned short*)(ws + (13u << 20) + 65536);  // 64 KB
  unsigned short* weff   = (unsigned short*)(ws + (13u << 20) + 131072); // 256 KB
  float*          beff   = (float*)(ws + (13u << 20) + 131072 + 262144); // 2 KB
  float*          sbuf   = (float*)(ws + (14u << 20));                   // 64 KB
  unsigned short* Wbf    = (unsigned short*)(ws + (14u << 20) + 131072); // 192 KB
  unsigned char*  P8buf  = (unsigned char*)(ws + (16u << 20));           // up to 33.5 MB
  unsigned short* Tt     = (unsigned short*)P8buf;  // 8 MB; dead before kA writes

  const size_t pPerBatch = (size_t)2048 * 2048;     // 4 MB fp8 per batch
  size_t avail = ws_size > (16u << 20) ? ws_size - (16u << 20) : 0;
  int nb = 8, bshift = 3;
  while (nb > 1 && (size_t)nb * pPerBatch > avail){ nb >>= 1; bshift--; }

  hipMemsetAsync(ws + (12u << 20), 0, 16384, stream);   // pooledEnc + tmaxe floors
  k0_tt<<<dim3(1120), dim3(256), 0, stream>>>(tmpl, Tt, pooledEnc, qw, kw, vw, Wbf);
  k23_qkv_params<<<dim3(512 + 2097), dim3(256), 0, stream>>>(Wbf, Tt, Q, K, V8,
                                                             pooledEnc, cw, cb, params);
  for (int b0 = 0; b0 < 8; b0 += nb){
    kA_scores<<<dim3(64 * nb), dim3(512), 0, stream>>>(Q, K, P8buf, sbuf, b0, bshift);
    kB_pv<<<dim3(64 * nb), dim3(256), 0, stream>>>(P8buf, V8, sbuf, tmaxe, b0, bshift);
  }
  k5_weff<<<dim3(64, 8), dim3(256), 0, stream>>>(pw, pb, tmaxe, params, weff, beff, w0b, w1b);
  k6_main<<<dim3(64, 8), dim3(512), 0, stream>>>(scene, weff, beff, w0b, w1b, params, out);
}